// Round 7
// baseline (284530.615 us; speedup 1.0000x reference)
//
#include <hip/hip_runtime.h>
#include <cstdint>
#include <cstddef>

// ---------------------------------------------------------------------------
// Seq2SeqNet: bidir GRU encoder (1024 steps) + attention GRU greedy decoder
// (256 steps). ALL math fp32, arithmetic chains identical to the round-5
// PASSING kernel (greedy argmax feedback: ANY reassociation can flip a token).
//
// Round-5 lesson (counters): per-b blocks = 64 CUs used + 64x weight traffic
// -> 470us/step. This revision spreads each b over 4 blocks (grid 4*BC=256
// blocks x 1024 thr = all 256 CUs, 16 waves/CU) with cheap per-group flag
// barriers (monotone atomic counter; ~1us; NOT grid.sync which measured
// 6-95us). Work is split by ROWS (independent tasks, FP-exact remap); the 6
// GRU gate dot-chains go one-accumulator-per-thread (chain order untouched);
// small per-b reductions (softmax combine, argmax) run redundantly in all 4
// blocks (identical inputs -> identical results). Cooperative launch only to
// guarantee co-residency; fallback = round-5's proven per-b kernel.
// [Resubmission: round-6 bench was an infra failure ("container failed
//  twice", same signature as round 3 whose identical resubmit then passed).
//  Deadlock surface re-audited: barrier counts uniform, coop launch
//  guarantees co-residency, all conditional __syncthreads block-uniform.]
// ---------------------------------------------------------------------------

constexpr int kH = 512, kH2 = 256, kVC = 2000, kB = 64, kLIN = 1024, kT = 256;
constexpr int kSTART = 1;
constexpr int kGRP = 4;          // blocks per batch element

// -------------------------------------------------------------------- zero
__global__ __launch_bounds__(256) void k_zero(float* p, int n) {
  int i = blockIdx.x * 256 + threadIdx.x;
  if (i < n) p[i] = 0.f;
}

// ------------------------------------------- encoder input-gate token table
__global__ __launch_bounds__(256)
void k_gi_table(const float* emb_jamo, const float* Wf, const float* Wb,
                const float* bihf, const float* bihb, float* gi) {
  int v = blockIdx.x >> 1, d = blockIdx.x & 1;
  const float* W = d ? Wb : Wf;
  const float* bih = d ? bihb : bihf;
  __shared__ float x[kH];
  for (int k = threadIdx.x; k < kH; k += 256) x[k] = emb_jamo[v * kH + k];
  __syncthreads();
  for (int j = threadIdx.x; j < 3 * kH2; j += 256) {
    float acc = bih[j];
    const float* row = W + (size_t)j * kH;
    for (int k = 0; k < kH; k += 4) {
      float4 f = *(const float4*)(row + k);
      acc += x[k] * f.x + x[k + 1] * f.y + x[k + 2] * f.z + x[k + 3] * f.w;
    }
    gi[(size_t)(v * 2 + d) * 768 + j] = acc;
  }
}

// ------------------ decoder embedding tables (bias folded)
__global__ __launch_bounds__(256)
void k_ac_emb(const float* emb_char, const float* attn_W, const float* attn_b,
              const float* comb_W, const float* comb_b, float* A, float* C) {
  int v = blockIdx.x;
  __shared__ float x[kH];
  for (int k = threadIdx.x; k < kH; k += 256) x[k] = emb_char[v * kH + k];
  __syncthreads();
  for (int j = threadIdx.x; j < kH; j += 256) {
    float a = attn_b[j], c = comb_b[j];
    const float* ra = attn_W + (size_t)j * 1024;
    const float* rc = comb_W + (size_t)j * 1024;
    for (int k = 0; k < kH; k += 4) {
      float4 fa = *(const float4*)(ra + k), fc = *(const float4*)(rc + k);
      a += x[k] * fa.x + x[k + 1] * fa.y + x[k + 2] * fa.z + x[k + 3] * fa.w;
      c += x[k] * fc.x + x[k + 1] * fc.y + x[k + 2] * fc.z + x[k + 3] * fc.w;
    }
    A[(size_t)v * kH + j] = a;
    C[(size_t)v * kH + j] = c;
  }
}

// ================= persistent per-(b,dir) encoder (round-5, verified) ======
__global__ __launch_bounds__(256)
void k_enc_pb(const int* tokens, const float* Whf, const float* Whb,
              const float* bhhf, const float* bhhb, const float* gi,
              float* enc, int b0) {
  int b = blockIdx.x >> 1, d = blockIdx.x & 1;
  int u = threadIdx.x;
  const float* Whh = d ? Whb : Whf;
  const float* bhh = d ? bhhb : bhhf;
  __shared__ float hsh[kH2];
  hsh[u] = 0.f;
  __syncthreads();
  const float* wr = Whh + (size_t)(0 * kH2 + u) * kH2;
  const float* wz = Whh + (size_t)(1 * kH2 + u) * kH2;
  const float* wn = Whh + (size_t)(2 * kH2 + u) * kH2;
  float br = bhh[u], bz = bhh[kH2 + u], bn = bhh[2 * kH2 + u];
  const int* myTok = tokens + (size_t)(b0 + b) * kLIN;
  float* encCol = enc + (size_t)b * kLIN * kH + d * kH2 + u;
  for (int t = 0; t < kLIN; ++t) {
    float ar = br, az = bz, an = bn;
    for (int k = 0; k < kH2; k += 4) {
      float4 fr = *(const float4*)(wr + k);
      float4 fz = *(const float4*)(wz + k);
      float4 fn = *(const float4*)(wn + k);
      float h0v = hsh[k], h1v = hsh[k + 1], h2v = hsh[k + 2], h3v = hsh[k + 3];
      ar += h0v * fr.x + h1v * fr.y + h2v * fr.z + h3v * fr.w;
      az += h0v * fz.x + h1v * fz.y + h2v * fz.z + h3v * fz.w;
      an += h0v * fn.x + h1v * fn.y + h2v * fn.z + h3v * fn.w;
    }
    int v = myTok[t];
    const float* git = gi + (size_t)(v * 2 + d) * 768;
    float r = 1.f / (1.f + expf(-(git[u] + ar)));
    float z = 1.f / (1.f + expf(-(git[kH2 + u] + az)));
    float n = tanhf(git[2 * kH2 + u] + r * an);
    float hprev = hsh[u];
    float hnew = (1.f - z) * n + z * hprev;
    __syncthreads();
    hsh[u] = hnew;
    encCol[(size_t)t * kH] = hnew;
    __syncthreads();
  }
}

// ================= grouped decoder: 4 blocks per b, flag barriers ==========
__global__ __launch_bounds__(1024, 1)
void k_dec_grp(const float* encAll, const float* cW, const float* Ctab,
               const float* dWi, const float* dWh, const float* dbi, const float* dbh,
               const float* oW, const float* ob, const float* aW, const float* Atab,
               const int* targets, const float* maskp,
               float* sc_g, float* pm_g, float* pd_g, float* pctx_g,
               float* gt_g, float* hG, float* lg_g, float* key_g,
               unsigned* flags, float* loss, float* out0, float* out1,
               int BC, int b0) {
  int b = blockIdx.x % BC;
  int j = blockIdx.x / BC;          // 0..3 (stride-BC grouping: same-XCD bias)
  bool blk0 = (j == 0);
  int tid = threadIdx.x;
  int sg = tid >> 8, stid = tid & 255;
  int lane = stid & 63, w = stid >> 6, hl = lane & 31, half = lane >> 5;
  int p = sg & 1, hr = sg >> 1;

  __shared__ float s_tile[2][128], e_tile[2][128], red[2][128];
  __shared__ float ctxl[kH], gtl[kH], hpl[kH], hnl[kH];
  __shared__ float cacc[6][128];
  __shared__ float rv[256]; __shared__ int ri[256]; __shared__ float rs[256];
  __shared__ float f8[8], MD[2];

  const float* encB = encAll + (size_t)b * kLIN * kH;
  int gb = b0 + b;
  unsigned* ctr = flags + (size_t)b * 32;
  unsigned nbar = 0;
  int tokr = kSTART;

  // group barrier: monotone counter, release/acquire via threadfence
  auto GBAR = [&]() {
    __threadfence();
    __syncthreads();
    ++nbar;
    if (tid == 0) {
      atomicAdd(ctr, 1u);
      unsigned tgt = (unsigned)kGRP * nbar;
      while (__hip_atomic_load(ctr, __ATOMIC_RELAXED, __HIP_MEMORY_SCOPE_AGENT) < tgt)
        __builtin_amdgcn_s_sleep(2);
    }
    __syncthreads();
    __threadfence();
  };

  // ---- prologue: h0 = enc[b][1023]; key = A[START] + h0 . aW[:,512:] -----
  if (tid < kH) hpl[tid] = encB[(size_t)(kLIN - 1) * kH + tid];
  __syncthreads();
  if (blk0 && tid < kH) hG[((size_t)b * 2 + 0) * kH + tid] = hpl[tid];
  if (tid < 128) {
    int jr = j * 128 + tid;
    const float* row = aW + (size_t)jr * 1024 + 512;
    float acc = Atab[(size_t)kSTART * kH + jr];
    for (int k = 0; k < kH; k += 4) {
      float4 f = *(const float4*)(row + k);
      acc += hpl[k] * f.x + hpl[k + 1] * f.y + hpl[k + 2] * f.z + hpl[k + 3] * f.w;
    }
    key_g[(size_t)b * kH + jr] = acc;
  }
  GBAR();

  for (int t = 0; t < kT; ++t) {
    int pp = t & 1, np = 1 - pp;

    // ============ phase A: tiles 2j,2j+1 (rows split across sg pairs) =====
    {
      float kreg[16];
#pragma unroll
      for (int m = 0; m < 16; m += 4)
        *(float4*)(kreg + m) = *(const float4*)(key_g + (size_t)b * kH + hl * 16 + m);
      int lt = 2 * j + p;
      for (int ii = 0; ii < 8; ii += 2) {      // this sg's 8 of 16 i-values
        int i0 = hr * 8 + ii;
        float4 v[2][4];
#pragma unroll
        for (int jj = 0; jj < 2; jj++) {
          int ll = w * 32 + (i0 + jj) * 2 + half;
          const float* row = encB + (size_t)(lt * 128 + ll) * kH + hl * 16;
#pragma unroll
          for (int m = 0; m < 4; m++) v[jj][m] = *(const float4*)(row + m * 4);
        }
#pragma unroll
        for (int jj = 0; jj < 2; jj++) {
          int ll = w * 32 + (i0 + jj) * 2 + half;
          float acc = 0.f;
#pragma unroll
          for (int m = 0; m < 4; m++)
            acc += v[jj][m].x * kreg[4 * m] + v[jj][m].y * kreg[4 * m + 1] +
                   v[jj][m].z * kreg[4 * m + 2] + v[jj][m].w * kreg[4 * m + 3];
#pragma unroll
          for (int m2 = 16; m2 > 0; m2 >>= 1) acc += __shfl_xor(acc, m2, 32);
          if (hl == 0) { s_tile[p][ll] = acc; sc_g[(size_t)b * kLIN + lt * 128 + ll] = acc; }
        }
      }
      __syncthreads();
      // softmax trees: sg0 -> tile p=0, sg1 -> tile p=1 (verbatim shape)
      if (sg < 2 && stid < 128) red[sg][stid] = s_tile[sg][stid];
      __syncthreads();
      for (int s = 64; s > 0; s >>= 1) {
        if (sg < 2 && stid < s) red[sg][stid] = fmaxf(red[sg][stid], red[sg][stid + s]);
        __syncthreads();
      }
      float mt = red[p][0];
      __syncthreads();
      if (sg < 2 && stid < 128) { e_tile[sg][stid] = expf(s_tile[sg][stid] - mt); red[sg][stid] = e_tile[sg][stid]; }
      __syncthreads();
      for (int s = 64; s > 0; s >>= 1) {
        if (sg < 2 && stid < s) red[sg][stid] += red[sg][stid + s];
        __syncthreads();
      }
      float dt = red[p][0];
      if (sg < 2 && stid == 0) { pm_g[b * 8 + 2 * j + sg] = mt; pd_g[b * 8 + 2 * j + sg] = dt; }
      __syncthreads();
      // ctx partials: one column per thread (per-column chain order verbatim)
      {
        int p2 = tid >> 9;                    // tile 2j+p2
        int cc = tid & 511;
        int lt2 = 2 * j + p2;
        const float* base = encB + (size_t)(lt2 * 128) * kH + cc;
        float c = 0.f;
        for (int l0 = 0; l0 < 128; l0 += 4) {
          float x0 = base[(size_t)(l0 + 0) * kH];
          float x1 = base[(size_t)(l0 + 1) * kH];
          float x2 = base[(size_t)(l0 + 2) * kH];
          float x3 = base[(size_t)(l0 + 3) * kH];
          c += e_tile[p2][l0] * x0;
          c += e_tile[p2][l0 + 1] * x1;
          c += e_tile[p2][l0 + 2] * x2;
          c += e_tile[p2][l0 + 3] * x3;
        }
        pctx_g[((size_t)b * 8 + lt2) * kH + cc] = c;
      }
    }
    GBAR();

    // ============ combine (redundant per block) + out1(blk0) + gt slice ===
    if (tid == 0) {
      float M = -1e30f;
      for (int i = 0; i < 8; i++) M = fmaxf(M, pm_g[b * 8 + i]);
      float D = 0.f;
      for (int i = 0; i < 8; i++) {
        float f = expf(pm_g[b * 8 + i] - M);
        f8[i] = f; D += f * pd_g[b * 8 + i];
      }
      MD[0] = M; MD[1] = 1.f / D;
    }
    __syncthreads();
    float M = MD[0], invD = MD[1];
    if (tid < kH) {       // full ctxl per block (per-column chain verbatim)
      int cc = tid;
      float c = 0.f;
      for (int i = 0; i < 8; i++) c += f8[i] * pctx_g[((size_t)b * 8 + i) * kH + cc];
      ctxl[cc] = c * invD;
    }
    if (blk0)
      out1[((size_t)gb * kLIN + tid) * kT + t] = expf(sc_g[(size_t)b * kLIN + tid] - M) * invD;
    __syncthreads();
    if (tid < 128) {      // gt rows j*128..+128 (verbatim dot)
      int jr = j * 128 + tid;
      const float* row = cW + (size_t)jr * 1024 + 512;
      float acc = Ctab[(size_t)tokr * kH + jr];
      for (int k = 0; k < kH; k += 4) {
        float4 f = *(const float4*)(row + k);
        acc += ctxl[k] * f.x + ctxl[k + 1] * f.y + ctxl[k + 2] * f.z + ctxl[k + 3] * f.w;
      }
      gt_g[(size_t)b * kH + jr] = fmaxf(acc, 0.f);
    }
    GBAR();

    // ============ phase C: GRU u-slice; 6 gate chains, 1 thread each ======
    if (tid < kH) {
      hpl[tid] = hG[((size_t)b * 2 + pp) * kH + tid];
      gtl[tid] = gt_g[(size_t)b * kH + tid];
    }
    __syncthreads();
    if (tid < 768) {
      int gate = tid >> 7, ul = tid & 127;
      int u = j * 128 + ul;
      const float* row; const float* vec; float acc;
      if (gate < 3) { row = dWi + (size_t)(gate * kH + u) * kH; vec = gtl; acc = dbi[gate * kH + u]; }
      else { int g2 = gate - 3; row = dWh + (size_t)(g2 * kH + u) * kH; vec = hpl; acc = dbh[g2 * kH + u]; }
      for (int k = 0; k < kH; k += 4) {
        float4 f = *(const float4*)(row + k);
        acc += vec[k] * f.x + vec[k + 1] * f.y + vec[k + 2] * f.z + vec[k + 3] * f.w;
      }
      cacc[gate][ul] = acc;
    }
    __syncthreads();
    if (tid < 128) {
      int u = j * 128 + tid;
      float air = cacc[0][tid], aiz = cacc[1][tid], ain = cacc[2][tid];
      float ahr = cacc[3][tid], ahz = cacc[4][tid], ahn = cacc[5][tid];
      float rr = 1.f / (1.f + expf(-(air + ahr)));
      float zz = 1.f / (1.f + expf(-(aiz + ahz)));
      float nn = tanhf(ain + rr * ahn);
      float hp = hpl[u];
      hG[((size_t)b * 2 + np) * kH + u] = (1.f - zz) * nn + zz * hp;
    }
    GBAR();

    // ============ phase D: logits, tiles 2j,2j+1, rows split sg pairs =====
    if (tid < kH) hnl[tid] = hG[((size_t)b * 2 + np) * kH + tid];
    __syncthreads();
    {
      float hreg[16];
#pragma unroll
      for (int m = 0; m < 16; m += 4) *(float4*)(hreg + m) = *(const float4*)(&hnl[hl * 16 + m]);
      int ct = 2 * j + p;
      int c0 = ct * 250;
      for (int ii = 0; ii < 16; ii += 2) {    // this sg's 16 of 32 i-values
        int i0 = hr * 16 + ii;
        int ca = c0 + (i0 + 0) * 8 + w * 2 + half;
        int cb = c0 + (i0 + 1) * 8 + w * 2 + half;
        int cca = ca < kVC ? ca : kVC - 1;
        int ccb = cb < kVC ? cb : kVC - 1;
        float4 va[4], vb[4];
        const float* rowa = oW + (size_t)cca * kH + hl * 16;
        const float* rowb = oW + (size_t)ccb * kH + hl * 16;
#pragma unroll
        for (int m = 0; m < 4; m++) { va[m] = *(const float4*)(rowa + m * 4); vb[m] = *(const float4*)(rowb + m * 4); }
        float acca = 0.f, accb = 0.f;
#pragma unroll
        for (int m = 0; m < 4; m++)
          acca += va[m].x * hreg[4 * m] + va[m].y * hreg[4 * m + 1] +
                  va[m].z * hreg[4 * m + 2] + va[m].w * hreg[4 * m + 3];
#pragma unroll
        for (int m = 0; m < 4; m++)
          accb += vb[m].x * hreg[4 * m] + vb[m].y * hreg[4 * m + 1] +
                  vb[m].z * hreg[4 * m + 2] + vb[m].w * hreg[4 * m + 3];
#pragma unroll
        for (int m2 = 16; m2 > 0; m2 >>= 1) acca += __shfl_xor(acca, m2, 32);
#pragma unroll
        for (int m2 = 16; m2 > 0; m2 >>= 1) accb += __shfl_xor(accb, m2, 32);
        if (ca < c0 + 250 && hl == 0) lg_g[(size_t)b * kVC + ca] = acca + ob[ca];
        if (cb < c0 + 250 && hl == 0) lg_g[(size_t)b * kVC + cb] = accb + ob[cb];
      }
    }
    GBAR();

    // ============ phase E: argmax (redundant) + lse/out0/loss (blk0) + key =
    {
      const float* lrow = lg_g + (size_t)b * kVC;
      float xv[8];
      if (tid < 256) {
        float bv = -3.4e38f; int bi = kVC;
#pragma unroll
        for (int i = 0; i < 8; i++) {
          int c = tid + i * 256;
          float x = (c < kVC) ? lrow[c] : -3.4e38f;
          xv[i] = x;
          if (x > bv) { bv = x; bi = c; }
        }
        rv[tid] = bv; ri[tid] = bi;
      }
      __syncthreads();
      for (int s = 128; s > 0; s >>= 1) {
        if (tid < s) {
          float v2 = rv[tid + s]; int i2 = ri[tid + s];
          if (v2 > rv[tid] || (v2 == rv[tid] && i2 < ri[tid])) { rv[tid] = v2; ri[tid] = i2; }
        }
        __syncthreads();
      }
      float Me = rv[0]; int nt = ri[0];
      if (blk0) {
        if (tid < 256) {
          float se = 0.f;
#pragma unroll
          for (int i = 0; i < 8; i++) { int c = tid + i * 256; if (c < kVC) se += expf(xv[i] - Me); }
          rs[tid] = se;
        }
        __syncthreads();
        for (int s = 128; s > 0; s >>= 1) {
          if (tid < s) rs[tid] += rs[tid + s];
          __syncthreads();
        }
        float lse = Me + logf(rs[0]);
        for (int c = tid; c < kVC; c += 1024)
          out0[((size_t)gb * kT + t) * kVC + c] = lrow[c] - lse;
        if (tid == 0) {
          int tg = targets[(size_t)gb * kT + t];
          float mk = maskp[(size_t)gb * kT + t];
          atomicAdd(loss, (lse - lrow[tg]) * mk * (1.f / 16384.f));  // /B /T
        }
      }
      tokr = nt;
      if (tid < 128) {    // next key rows (verbatim chain; h from hnl)
        int jr = j * 128 + tid;
        const float* row = aW + (size_t)jr * 1024 + 512;
        float acc = Atab[(size_t)nt * kH + jr];
        for (int k = 0; k < kH; k += 4) {
          float4 f = *(const float4*)(row + k);
          acc += hnl[k] * f.x + hnl[k + 1] * f.y + hnl[k + 2] * f.z + hnl[k + 3] * f.w;
        }
        key_g[(size_t)b * kH + jr] = acc;
      }
    }
    GBAR();
  }
}

// ================= round-5 per-b decoder (verified) — fallback =============
__global__ __launch_bounds__(1024, 1)
void k_dec_pb(const float* encAll, const float* cW, const float* Ctab,
              const float* dWi, const float* dWh, const float* dbi, const float* dbh,
              const float* oW, const float* ob, const float* aW, const float* Atab,
              const int* targets, const float* maskp,
              float* loss, float* out0, float* out1, int b0) {
  int b = blockIdx.x;
  int tid = threadIdx.x;
  int sg = tid >> 8, stid = tid & 255;
  int lane = stid & 63, w = stid >> 6, hl = lane & 31, half = lane >> 5;

  __shared__ float s_tile[4][128], e_tile[4][128], red[4][128];
  __shared__ float pm_s[8], pd_s[8];
  __shared__ float pctx_s[8][kH];
  __shared__ __align__(16) float sc_all[kLIN];
  __shared__ __align__(16) float key_s[kH];
  __shared__ __align__(16) float hbuf[2][kH];
  __shared__ __align__(16) float ctxl[kH];
  __shared__ __align__(16) float gt_s[kH];
  __shared__ float lg_s[kVC];
  __shared__ float rv[256]; __shared__ int ri[256]; __shared__ float rs[256];
  __shared__ float MD[2]; __shared__ float f8[8];
  __shared__ int tok_s;

  const float* encB = encAll + (size_t)b * kLIN * kH;
  int gb = b0 + b;

  for (int k = tid; k < kH; k += 1024) hbuf[0][k] = encB[(size_t)(kLIN - 1) * kH + k];
  if (tid == 0) tok_s = kSTART;
  __syncthreads();
  if (tid < kH) {
    int j = tid;
    const float* row = aW + (size_t)j * 1024 + 512;
    float acc = Atab[(size_t)kSTART * kH + j];
    for (int k = 0; k < kH; k += 4) {
      float4 f = *(const float4*)(row + k);
      acc += hbuf[0][k] * f.x + hbuf[0][k + 1] * f.y + hbuf[0][k + 2] * f.z + hbuf[0][k + 3] * f.w;
    }
    key_s[j] = acc;
  }
  __syncthreads();

  for (int t = 0; t < kT; ++t) {
    int pp = t & 1;
    const float* hprev = hbuf[pp];
    float* hnew = hbuf[1 - pp];
    float kreg[16];
#pragma unroll
    for (int m = 0; m < 16; m += 4) *(float4*)(kreg + m) = *(const float4*)(key_s + hl * 16 + m);
    for (int r = 0; r < 2; ++r) {
      int lt = sg + r * 4;
      for (int i0 = 0; i0 < 16; i0 += 2) {
        float4 v[2][4];
#pragma unroll
        for (int j = 0; j < 2; j++) {
          int ll = w * 32 + (i0 + j) * 2 + half;
          const float* row = encB + (size_t)(lt * 128 + ll) * kH + hl * 16;
#pragma unroll
          for (int m = 0; m < 4; m++) v[j][m] = *(const float4*)(row + m * 4);
        }
#pragma unroll
        for (int j = 0; j < 2; j++) {
          int ll = w * 32 + (i0 + j) * 2 + half;
          float acc = 0.f;
#pragma unroll
          for (int m = 0; m < 4; m++)
            acc += v[j][m].x * kreg[4 * m] + v[j][m].y * kreg[4 * m + 1] +
                   v[j][m].z * kreg[4 * m + 2] + v[j][m].w * kreg[4 * m + 3];
#pragma unroll
          for (int m2 = 16; m2 > 0; m2 >>= 1) acc += __shfl_xor(acc, m2, 32);
          if (hl == 0) { s_tile[sg][ll] = acc; sc_all[lt * 128 + ll] = acc; }
        }
      }
      __syncthreads();
      if (stid < 128) red[sg][stid] = s_tile[sg][stid];
      __syncthreads();
      for (int s = 64; s > 0; s >>= 1) {
        if (stid < s) red[sg][stid] = fmaxf(red[sg][stid], red[sg][stid + s]);
        __syncthreads();
      }
      float mt = red[sg][0];
      __syncthreads();
      if (stid < 128) { e_tile[sg][stid] = expf(s_tile[sg][stid] - mt); red[sg][stid] = e_tile[sg][stid]; }
      __syncthreads();
      for (int s = 64; s > 0; s >>= 1) {
        if (stid < s) red[sg][stid] += red[sg][stid + s];
        __syncthreads();
      }
      float dt = red[sg][0];
      int h0i = stid * 2;
      float cx = 0.f, cy = 0.f;
      const float* base = encB + (size_t)(lt * 128) * kH + h0i;
      for (int l0 = 0; l0 < 128; l0 += 4) {
        float2 v0 = *(const float2*)(base + (size_t)(l0 + 0) * kH);
        float2 v1 = *(const float2*)(base + (size_t)(l0 + 1) * kH);
        float2 v2 = *(const float2*)(base + (size_t)(l0 + 2) * kH);
        float2 v3 = *(const float2*)(base + (size_t)(l0 + 3) * kH);
        float e0 = e_tile[sg][l0], e1 = e_tile[sg][l0 + 1];
        float e2 = e_tile[sg][l0 + 2], e3 = e_tile[sg][l0 + 3];
        cx += e0 * v0.x; cy += e0 * v0.y;
        cx += e1 * v1.x; cy += e1 * v1.y;
        cx += e2 * v2.x; cy += e2 * v2.y;
        cx += e3 * v3.x; cy += e3 * v3.y;
      }
      pctx_s[lt][h0i] = cx; pctx_s[lt][h0i + 1] = cy;
      if (stid == 0) { pm_s[lt] = mt; pd_s[lt] = dt; }
      __syncthreads();
    }
    if (tid == 0) {
      float M = -1e30f;
      for (int i = 0; i < 8; i++) M = fmaxf(M, pm_s[i]);
      float D = 0.f;
      for (int i = 0; i < 8; i++) {
        float f = expf(pm_s[i] - M);
        f8[i] = f; D += f * pd_s[i];
      }
      MD[0] = M; MD[1] = 1.f / D;
    }
    __syncthreads();
    float M = MD[0], invD = MD[1];
    if (tid < 256) {
      int h0i = tid * 2;
      float cx = 0.f, cy = 0.f;
      for (int i = 0; i < 8; i++) { cx += f8[i] * pctx_s[i][h0i]; cy += f8[i] * pctx_s[i][h0i + 1]; }
      ctxl[h0i] = cx * invD; ctxl[h0i + 1] = cy * invD;
    }
    out1[((size_t)gb * kLIN + tid) * kT + t] = expf(sc_all[tid] - M) * invD;
    __syncthreads();
    if (tid < kH) {
      int j = tid, tk = tok_s;
      const float* row = cW + (size_t)j * 1024 + 512;
      float acc = Ctab[(size_t)tk * kH + j];
      for (int k = 0; k < kH; k += 4) {
        float4 f = *(const float4*)(row + k);
        acc += ctxl[k] * f.x + ctxl[k + 1] * f.y + ctxl[k + 2] * f.z + ctxl[k + 3] * f.w;
      }
      gt_s[j] = fmaxf(acc, 0.f);
    }
    __syncthreads();
    if (tid < kH) {
      int u = tid;
      float air = dbi[u], aiz = dbi[kH + u], ain = dbi[2 * kH + u];
      float ahr = dbh[u], ahz = dbh[kH + u], ahn = dbh[2 * kH + u];
      const float* wir = dWi + (size_t)(0 * kH + u) * kH;
      const float* wiz = dWi + (size_t)(1 * kH + u) * kH;
      const float* win = dWi + (size_t)(2 * kH + u) * kH;
      const float* whr = dWh + (size_t)(0 * kH + u) * kH;
      const float* whz = dWh + (size_t)(1 * kH + u) * kH;
      const float* whn = dWh + (size_t)(2 * kH + u) * kH;
      for (int k = 0; k < kH; k += 4) {
        float4 fir = *(const float4*)(wir + k), fiz = *(const float4*)(wiz + k), fin = *(const float4*)(win + k);
        float4 fhr = *(const float4*)(whr + k), fhz = *(const float4*)(whz + k), fhn = *(const float4*)(whn + k);
        float g0 = gt_s[k], g1 = gt_s[k + 1], g2 = gt_s[k + 2], g3 = gt_s[k + 3];
        float h0v = hprev[k], h1v = hprev[k + 1], h2v = hprev[k + 2], h3v = hprev[k + 3];
        air += g0 * fir.x + g1 * fir.y + g2 * fir.z + g3 * fir.w;
        aiz += g0 * fiz.x + g1 * fiz.y + g2 * fiz.z + g3 * fiz.w;
        ain += g0 * fin.x + g1 * fin.y + g2 * fin.z + g3 * fin.w;
        ahr += h0v * fhr.x + h1v * fhr.y + h2v * fhr.z + h3v * fhr.w;
        ahz += h0v * fhz.x + h1v * fhz.y + h2v * fhz.z + h3v * fhz.w;
        ahn += h0v * fhn.x + h1v * fhn.y + h2v * fhn.z + h3v * fhn.w;
      }
      float rr = 1.f / (1.f + expf(-(air + ahr)));
      float zz = 1.f / (1.f + expf(-(aiz + ahz)));
      float nn = tanhf(ain + rr * ahn);
      float hp = hprev[u];
      hnew[u] = (1.f - zz) * nn + zz * hp;
    }
    __syncthreads();
    {
      float hreg[16];
#pragma unroll
      for (int m = 0; m < 16; m += 4) *(float4*)(hreg + m) = *(const float4*)(&hnew[hl * 16 + m]);
      for (int r = 0; r < 2; ++r) {
        int ct = sg + r * 4;
        int c0 = ct * 250;
        for (int i0 = 0; i0 < 32; i0 += 2) {
          int ca = c0 + (i0 + 0) * 8 + w * 2 + half;
          int cb = c0 + (i0 + 1) * 8 + w * 2 + half;
          int cca = ca < kVC ? ca : kVC - 1;
          int ccb = cb < kVC ? cb : kVC - 1;
          float4 va[4], vb[4];
          const float* rowa = oW + (size_t)cca * kH + hl * 16;
          const float* rowb = oW + (size_t)ccb * kH + hl * 16;
#pragma unroll
          for (int m = 0; m < 4; m++) { va[m] = *(const float4*)(rowa + m * 4); vb[m] = *(const float4*)(rowb + m * 4); }
          float acca = 0.f, accb = 0.f;
#pragma unroll
          for (int m = 0; m < 4; m++)
            acca += va[m].x * hreg[4 * m] + va[m].y * hreg[4 * m + 1] +
                    va[m].z * hreg[4 * m + 2] + va[m].w * hreg[4 * m + 3];
#pragma unroll
          for (int m = 0; m < 4; m++)
            accb += vb[m].x * hreg[4 * m] + vb[m].y * hreg[4 * m + 1] +
                    vb[m].z * hreg[4 * m + 2] + vb[m].w * hreg[4 * m + 3];
#pragma unroll
          for (int m2 = 16; m2 > 0; m2 >>= 1) acca += __shfl_xor(acca, m2, 32);
#pragma unroll
          for (int m2 = 16; m2 > 0; m2 >>= 1) accb += __shfl_xor(accb, m2, 32);
          if (ca < c0 + 250 && hl == 0) lg_s[ca] = acca + ob[ca];
          if (cb < c0 + 250 && hl == 0) lg_s[cb] = accb + ob[cb];
        }
      }
    }
    __syncthreads();
    float xv[8];
    if (sg == 0) {
      float bv = -3.4e38f; int bi = kVC;
#pragma unroll
      for (int i = 0; i < 8; i++) {
        int c = stid + i * 256;
        float x = (c < kVC) ? lg_s[c] : -3.4e38f;
        xv[i] = x;
        if (x > bv) { bv = x; bi = c; }
      }
      rv[stid] = bv; ri[stid] = bi;
    }
    __syncthreads();
    for (int s = 128; s > 0; s >>= 1) {
      if (sg == 0 && stid < s) {
        float v2 = rv[stid + s]; int i2 = ri[stid + s];
        if (v2 > rv[stid] || (v2 == rv[stid] && i2 < ri[stid])) { rv[stid] = v2; ri[stid] = i2; }
      }
      __syncthreads();
    }
    float Me = rv[0]; int nt = ri[0];
    if (sg == 0) {
      float se = 0.f;
#pragma unroll
      for (int i = 0; i < 8; i++) { int c = stid + i * 256; if (c < kVC) se += expf(xv[i] - Me); }
      rs[stid] = se;
    }
    __syncthreads();
    for (int s = 128; s > 0; s >>= 1) {
      if (sg == 0 && stid < s) rs[stid] += rs[stid + s];
      __syncthreads();
    }
    float lse = Me + logf(rs[0]);
    for (int c = tid; c < kVC; c += 1024)
      out0[((size_t)gb * kT + t) * kVC + c] = lg_s[c] - lse;
    if (tid == 0) {
      tok_s = nt;
      int tg = targets[(size_t)gb * kT + t];
      float mk = maskp[(size_t)gb * kT + t];
      atomicAdd(loss, (lse - lg_s[tg]) * mk * (1.f / 16384.f));
    }
    if (tid < kH) {
      int j = tid;
      const float* row = aW + (size_t)j * 1024 + 512;
      float acc = Atab[(size_t)nt * kH + j];
      for (int k = 0; k < kH; k += 4) {
        float4 f = *(const float4*)(row + k);
        acc += hnew[k] * f.x + hnew[k + 1] * f.y + hnew[k + 2] * f.z + hnew[k + 3] * f.w;
      }
      key_s[j] = acc;
    }
    __syncthreads();
  }
}

__global__ void k_loss_out(float* dst, const float* loss) {
  if (threadIdx.x == 0 && blockIdx.x == 0) *dst = *loss;
}

// ---------------------------------------------------------------------------
static int g_coop = -1;      // -1 unknown, 1 works, 0 rejected -> fallback

extern "C" void kernel_launch(void* const* d_in, const int* in_sizes, int n_in,
                              void* d_out, int out_size, void* d_ws, size_t ws_size,
                              hipStream_t stream) {
  (void)in_sizes; (void)n_in;
  const int*   tok_in = (const int*)d_in[0];
  const int*   tgt    = (const int*)d_in[1];
  const float* mask   = (const float*)d_in[2];
  const float* emb_j  = (const float*)d_in[3];
  const float* emb_c  = (const float*)d_in[4];
  const float* eWif   = (const float*)d_in[5];
  const float* eWhf   = (const float*)d_in[6];
  const float* ebif   = (const float*)d_in[7];
  const float* ebhf   = (const float*)d_in[8];
  const float* eWib   = (const float*)d_in[9];
  const float* eWhb   = (const float*)d_in[10];
  const float* ebib   = (const float*)d_in[11];
  const float* ebhb   = (const float*)d_in[12];
  const float* dWi    = (const float*)d_in[13];
  const float* dWh    = (const float*)d_in[14];
  const float* dbi    = (const float*)d_in[15];
  const float* dbh    = (const float*)d_in[16];
  const float* aW     = (const float*)d_in[17];
  const float* ab     = (const float*)d_in[18];
  const float* cW     = (const float*)d_in[19];
  const float* cb     = (const float*)d_in[20];
  const float* oW     = (const float*)d_in[21];
  const float* ob     = (const float*)d_in[22];
  float* ws   = (float*)d_ws;
  float* out0 = (float*)d_out;
  float* out1 = out0 + (size_t)kB * kT * kVC;

  // ---- workspace layout (floats); scratch sized for BC=64 capacity
  const size_t GI   = 0;
  const size_t A    = GI + 107520;          // 70*2*768
  const size_t C    = A + 1024000;          // 2000*512
  const size_t SC   = C + 1024000;          // 64*1024
  const size_t PM   = SC + 65536;           // 64*8
  const size_t PD   = PM + 512;
  const size_t PCT  = PD + 512;             // 64*8*512
  const size_t GT   = PCT + 262144;         // 64*512
  const size_t HGo  = GT + 32768;           // 64*2*512
  const size_t LG   = HGo + 65536;          // 64*2000
  const size_t KEY  = LG + 128000;          // 64*512
  const size_t FLG  = KEY + 32768;          // 64*32 (uint counters, padded)
  const size_t LOSS = FLG + 2048;
  const size_t ENC  = LOSS + 1;             // + BC*1024*512

  int BC = 64;
  while (BC > 8 && (ENC + (size_t)BC * kLIN * kH) * sizeof(float) > ws_size) BC >>= 1;
  int NC = kB / BC;

  float* gi_p   = ws + GI;
  float* A_p    = ws + A;
  float* C_p    = ws + C;
  float* sc_p   = ws + SC;
  float* pm_p   = ws + PM;
  float* pd_p   = ws + PD;
  float* pct_p  = ws + PCT;
  float* gt_p   = ws + GT;
  float* hG_p   = ws + HGo;
  float* lg_p   = ws + LG;
  float* key_p  = ws + KEY;
  unsigned* flg = (unsigned*)(ws + FLG);
  float* loss_p = ws + LOSS;
  float* enc_p  = ws + ENC;

  k_zero<<<1, 256, 0, stream>>>(loss_p, 1);
  k_gi_table<<<140, 256, 0, stream>>>(emb_j, eWif, eWib, ebif, ebib, gi_p);
  k_ac_emb<<<2000, 256, 0, stream>>>(emb_c, aW, ab, cW, cb, A_p, C_p);

  for (int c = 0; c < NC; c++) {
    int b0 = c * BC;
    k_enc_pb<<<2 * BC, 256, 0, stream>>>(tok_in, eWhf, eWhb, ebhf, ebhb,
                                         gi_p, enc_p, b0);
    // zero group-barrier counters for this chunk
    k_zero<<<(2048 + 255) / 256, 256, 0, stream>>>(ws + FLG, 2048);

    bool dec_done = false;
    if (g_coop != 0) {
      void* dargs[] = {(void*)&enc_p, (void*)&cW, (void*)&C_p, (void*)&dWi,
                       (void*)&dWh, (void*)&dbi, (void*)&dbh, (void*)&oW,
                       (void*)&ob, (void*)&aW, (void*)&A_p, (void*)&tgt,
                       (void*)&mask, (void*)&sc_p, (void*)&pm_p, (void*)&pd_p,
                       (void*)&pct_p, (void*)&gt_p, (void*)&hG_p, (void*)&lg_p,
                       (void*)&key_p, (void*)&flg, (void*)&loss_p,
                       (void*)&out0, (void*)&out1, (void*)&BC, (void*)&b0};
      hipError_t e = hipLaunchCooperativeKernel(
          reinterpret_cast<void*>(k_dec_grp), dim3(kGRP * BC), dim3(1024),
          dargs, 0, stream);
      if (e == hipSuccess) { dec_done = true; if (g_coop < 0) g_coop = 1; }
      else { g_coop = 0; (void)hipGetLastError(); }
    }
    if (!dec_done) {
      k_dec_pb<<<BC, 1024, 0, stream>>>(enc_p, cW, C_p, dWi, dWh, dbi, dbh,
                                        oW, ob, aW, A_p, tgt, mask,
                                        loss_p, out0, out1, b0);
    }
  }
  k_loss_out<<<1, 64, 0, stream>>>(out0 + (size_t)out_size - 1, loss_p);
}

// Round 8
// 282854.590 us; speedup vs baseline: 1.0059x; 1.0059x over previous
//
#include <hip/hip_runtime.h>
#include <cstdint>
#include <cstddef>

// ---------------------------------------------------------------------------
// Seq2SeqNet: bidir GRU encoder (1024 steps) + attention GRU greedy decoder
// (256 steps). ALL math fp32, arithmetic chains identical to the round-5/7
// PASSING kernels (greedy argmax feedback: ANY reassociation can flip a
// token). Decoder: 4 blocks per batch element (grid 4*BC = 256 blocks x 1024
// thr = all CUs), per-group barriers.
//
// Round-7 lesson (counters: Occ 49.5%, VALUBusy 1.1%, 185us/barrier): the
// barrier spin used a RELAXED/AGENT atomic *load*, which is served from the
// local XCD's stale L2 (per-XCD L2s are NOT cross-coherent); progress waited
// on random L2 eviction. Fix: spin on a device-scope atomic RMW
// (atomicAdd(ctr,0) -- coherent by default on global [m20]) with s_sleep
// backoff. Everything else byte-identical to round 7 (verified correct).
// ---------------------------------------------------------------------------

constexpr int kH = 512, kH2 = 256, kVC = 2000, kB = 64, kLIN = 1024, kT = 256;
constexpr int kSTART = 1;
constexpr int kGRP = 4;          // blocks per batch element

// -------------------------------------------------------------------- zero
__global__ __launch_bounds__(256) void k_zero(float* p, int n) {
  int i = blockIdx.x * 256 + threadIdx.x;
  if (i < n) p[i] = 0.f;
}

// ------------------------------------------- encoder input-gate token table
__global__ __launch_bounds__(256)
void k_gi_table(const float* emb_jamo, const float* Wf, const float* Wb,
                const float* bihf, const float* bihb, float* gi) {
  int v = blockIdx.x >> 1, d = blockIdx.x & 1;
  const float* W = d ? Wb : Wf;
  const float* bih = d ? bihb : bihf;
  __shared__ float x[kH];
  for (int k = threadIdx.x; k < kH; k += 256) x[k] = emb_jamo[v * kH + k];
  __syncthreads();
  for (int j = threadIdx.x; j < 3 * kH2; j += 256) {
    float acc = bih[j];
    const float* row = W + (size_t)j * kH;
    for (int k = 0; k < kH; k += 4) {
      float4 f = *(const float4*)(row + k);
      acc += x[k] * f.x + x[k + 1] * f.y + x[k + 2] * f.z + x[k + 3] * f.w;
    }
    gi[(size_t)(v * 2 + d) * 768 + j] = acc;
  }
}

// ------------------ decoder embedding tables (bias folded)
__global__ __launch_bounds__(256)
void k_ac_emb(const float* emb_char, const float* attn_W, const float* attn_b,
              const float* comb_W, const float* comb_b, float* A, float* C) {
  int v = blockIdx.x;
  __shared__ float x[kH];
  for (int k = threadIdx.x; k < kH; k += 256) x[k] = emb_char[v * kH + k];
  __syncthreads();
  for (int j = threadIdx.x; j < kH; j += 256) {
    float a = attn_b[j], c = comb_b[j];
    const float* ra = attn_W + (size_t)j * 1024;
    const float* rc = comb_W + (size_t)j * 1024;
    for (int k = 0; k < kH; k += 4) {
      float4 fa = *(const float4*)(ra + k), fc = *(const float4*)(rc + k);
      a += x[k] * fa.x + x[k + 1] * fa.y + x[k + 2] * fa.z + x[k + 3] * fa.w;
      c += x[k] * fc.x + x[k + 1] * fc.y + x[k + 2] * fc.z + x[k + 3] * fc.w;
    }
    A[(size_t)v * kH + j] = a;
    C[(size_t)v * kH + j] = c;
  }
}

// ================= persistent per-(b,dir) encoder (round-5, verified) ======
__global__ __launch_bounds__(256)
void k_enc_pb(const int* tokens, const float* Whf, const float* Whb,
              const float* bhhf, const float* bhhb, const float* gi,
              float* enc, int b0) {
  int b = blockIdx.x >> 1, d = blockIdx.x & 1;
  int u = threadIdx.x;
  const float* Whh = d ? Whb : Whf;
  const float* bhh = d ? bhhb : bhhf;
  __shared__ float hsh[kH2];
  hsh[u] = 0.f;
  __syncthreads();
  const float* wr = Whh + (size_t)(0 * kH2 + u) * kH2;
  const float* wz = Whh + (size_t)(1 * kH2 + u) * kH2;
  const float* wn = Whh + (size_t)(2 * kH2 + u) * kH2;
  float br = bhh[u], bz = bhh[kH2 + u], bn = bhh[2 * kH2 + u];
  const int* myTok = tokens + (size_t)(b0 + b) * kLIN;
  float* encCol = enc + (size_t)b * kLIN * kH + d * kH2 + u;
  for (int t = 0; t < kLIN; ++t) {
    float ar = br, az = bz, an = bn;
    for (int k = 0; k < kH2; k += 4) {
      float4 fr = *(const float4*)(wr + k);
      float4 fz = *(const float4*)(wz + k);
      float4 fn = *(const float4*)(wn + k);
      float h0v = hsh[k], h1v = hsh[k + 1], h2v = hsh[k + 2], h3v = hsh[k + 3];
      ar += h0v * fr.x + h1v * fr.y + h2v * fr.z + h3v * fr.w;
      az += h0v * fz.x + h1v * fz.y + h2v * fz.z + h3v * fz.w;
      an += h0v * fn.x + h1v * fn.y + h2v * fn.z + h3v * fn.w;
    }
    int v = myTok[t];
    const float* git = gi + (size_t)(v * 2 + d) * 768;
    float r = 1.f / (1.f + expf(-(git[u] + ar)));
    float z = 1.f / (1.f + expf(-(git[kH2 + u] + az)));
    float n = tanhf(git[2 * kH2 + u] + r * an);
    float hprev = hsh[u];
    float hnew = (1.f - z) * n + z * hprev;
    __syncthreads();
    hsh[u] = hnew;
    encCol[(size_t)t * kH] = hnew;
    __syncthreads();
  }
}

// ================= grouped decoder: 4 blocks per b, flag barriers ==========
__global__ __launch_bounds__(1024, 1)
void k_dec_grp(const float* encAll, const float* cW, const float* Ctab,
               const float* dWi, const float* dWh, const float* dbi, const float* dbh,
               const float* oW, const float* ob, const float* aW, const float* Atab,
               const int* targets, const float* maskp,
               float* sc_g, float* pm_g, float* pd_g, float* pctx_g,
               float* gt_g, float* hG, float* lg_g, float* key_g,
               unsigned* flags, float* loss, float* out0, float* out1,
               int BC, int b0) {
  int b = blockIdx.x % BC;
  int j = blockIdx.x / BC;          // 0..3
  bool blk0 = (j == 0);
  int tid = threadIdx.x;
  int sg = tid >> 8, stid = tid & 255;
  int lane = stid & 63, w = stid >> 6, hl = lane & 31, half = lane >> 5;
  int p = sg & 1, hr = sg >> 1;

  __shared__ float s_tile[2][128], e_tile[2][128], red[2][128];
  __shared__ float ctxl[kH], gtl[kH], hpl[kH], hnl[kH];
  __shared__ float cacc[6][128];
  __shared__ float rv[256]; __shared__ int ri[256]; __shared__ float rs[256];
  __shared__ float f8[8], MD[2];

  const float* encB = encAll + (size_t)b * kLIN * kH;
  int gb = b0 + b;
  unsigned* ctr = flags + (size_t)b * 32;
  unsigned nbar = 0;
  int tokr = kSTART;

  // group barrier: monotone counter; spin uses device-scope atomic RMW
  // (atomicAdd(ctr,0)) -- a plain/relaxed load can be served from the local
  // XCD's stale L2 (not cross-coherent) and waits on random eviction (r7).
  auto GBAR = [&]() {
    __threadfence();
    __syncthreads();
    ++nbar;
    if (tid == 0) {
      atomicAdd(ctr, 1u);
      unsigned tgt = (unsigned)kGRP * nbar;
      while (atomicAdd(ctr, 0u) < tgt)
        __builtin_amdgcn_s_sleep(8);
    }
    __syncthreads();
    __threadfence();
  };

  // ---- prologue: h0 = enc[b][1023]; key = A[START] + h0 . aW[:,512:] -----
  if (tid < kH) hpl[tid] = encB[(size_t)(kLIN - 1) * kH + tid];
  __syncthreads();
  if (blk0 && tid < kH) hG[((size_t)b * 2 + 0) * kH + tid] = hpl[tid];
  if (tid < 128) {
    int jr = j * 128 + tid;
    const float* row = aW + (size_t)jr * 1024 + 512;
    float acc = Atab[(size_t)kSTART * kH + jr];
    for (int k = 0; k < kH; k += 4) {
      float4 f = *(const float4*)(row + k);
      acc += hpl[k] * f.x + hpl[k + 1] * f.y + hpl[k + 2] * f.z + hpl[k + 3] * f.w;
    }
    key_g[(size_t)b * kH + jr] = acc;
  }
  GBAR();

  for (int t = 0; t < kT; ++t) {
    int pp = t & 1, np = 1 - pp;

    // ============ phase A: tiles 2j,2j+1 (rows split across sg pairs) =====
    {
      float kreg[16];
#pragma unroll
      for (int m = 0; m < 16; m += 4)
        *(float4*)(kreg + m) = *(const float4*)(key_g + (size_t)b * kH + hl * 16 + m);
      int lt = 2 * j + p;
      for (int ii = 0; ii < 8; ii += 2) {      // this sg's 8 of 16 i-values
        int i0 = hr * 8 + ii;
        float4 v[2][4];
#pragma unroll
        for (int jj = 0; jj < 2; jj++) {
          int ll = w * 32 + (i0 + jj) * 2 + half;
          const float* row = encB + (size_t)(lt * 128 + ll) * kH + hl * 16;
#pragma unroll
          for (int m = 0; m < 4; m++) v[jj][m] = *(const float4*)(row + m * 4);
        }
#pragma unroll
        for (int jj = 0; jj < 2; jj++) {
          int ll = w * 32 + (i0 + jj) * 2 + half;
          float acc = 0.f;
#pragma unroll
          for (int m = 0; m < 4; m++)
            acc += v[jj][m].x * kreg[4 * m] + v[jj][m].y * kreg[4 * m + 1] +
                   v[jj][m].z * kreg[4 * m + 2] + v[jj][m].w * kreg[4 * m + 3];
#pragma unroll
          for (int m2 = 16; m2 > 0; m2 >>= 1) acc += __shfl_xor(acc, m2, 32);
          if (hl == 0) { s_tile[p][ll] = acc; sc_g[(size_t)b * kLIN + lt * 128 + ll] = acc; }
        }
      }
      __syncthreads();
      // softmax trees: sg0 -> tile p=0, sg1 -> tile p=1 (verbatim shape)
      if (sg < 2 && stid < 128) red[sg][stid] = s_tile[sg][stid];
      __syncthreads();
      for (int s = 64; s > 0; s >>= 1) {
        if (sg < 2 && stid < s) red[sg][stid] = fmaxf(red[sg][stid], red[sg][stid + s]);
        __syncthreads();
      }
      float mt = red[p][0];
      __syncthreads();
      if (sg < 2 && stid < 128) { e_tile[sg][stid] = expf(s_tile[sg][stid] - mt); red[sg][stid] = e_tile[sg][stid]; }
      __syncthreads();
      for (int s = 64; s > 0; s >>= 1) {
        if (sg < 2 && stid < s) red[sg][stid] += red[sg][stid + s];
        __syncthreads();
      }
      float dt = red[p][0];
      if (sg < 2 && stid == 0) { pm_g[b * 8 + 2 * j + sg] = mt; pd_g[b * 8 + 2 * j + sg] = dt; }
      __syncthreads();
      // ctx partials: one column per thread (per-column chain order verbatim)
      {
        int p2 = tid >> 9;                    // tile 2j+p2
        int cc = tid & 511;
        int lt2 = 2 * j + p2;
        const float* base = encB + (size_t)(lt2 * 128) * kH + cc;
        float c = 0.f;
        for (int l0 = 0; l0 < 128; l0 += 4) {
          float x0 = base[(size_t)(l0 + 0) * kH];
          float x1 = base[(size_t)(l0 + 1) * kH];
          float x2 = base[(size_t)(l0 + 2) * kH];
          float x3 = base[(size_t)(l0 + 3) * kH];
          c += e_tile[p2][l0] * x0;
          c += e_tile[p2][l0 + 1] * x1;
          c += e_tile[p2][l0 + 2] * x2;
          c += e_tile[p2][l0 + 3] * x3;
        }
        pctx_g[((size_t)b * 8 + lt2) * kH + cc] = c;
      }
    }
    GBAR();

    // ============ combine (redundant per block) + out1(blk0) + gt slice ===
    if (tid == 0) {
      float M = -1e30f;
      for (int i = 0; i < 8; i++) M = fmaxf(M, pm_g[b * 8 + i]);
      float D = 0.f;
      for (int i = 0; i < 8; i++) {
        float f = expf(pm_g[b * 8 + i] - M);
        f8[i] = f; D += f * pd_g[b * 8 + i];
      }
      MD[0] = M; MD[1] = 1.f / D;
    }
    __syncthreads();
    float M = MD[0], invD = MD[1];
    if (tid < kH) {       // full ctxl per block (per-column chain verbatim)
      int cc = tid;
      float c = 0.f;
      for (int i = 0; i < 8; i++) c += f8[i] * pctx_g[((size_t)b * 8 + i) * kH + cc];
      ctxl[cc] = c * invD;
    }
    if (blk0)
      out1[((size_t)gb * kLIN + tid) * kT + t] = expf(sc_g[(size_t)b * kLIN + tid] - M) * invD;
    __syncthreads();
    if (tid < 128) {      // gt rows j*128..+128 (verbatim dot)
      int jr = j * 128 + tid;
      const float* row = cW + (size_t)jr * 1024 + 512;
      float acc = Ctab[(size_t)tokr * kH + jr];
      for (int k = 0; k < kH; k += 4) {
        float4 f = *(const float4*)(row + k);
        acc += ctxl[k] * f.x + ctxl[k + 1] * f.y + ctxl[k + 2] * f.z + ctxl[k + 3] * f.w;
      }
      gt_g[(size_t)b * kH + jr] = fmaxf(acc, 0.f);
    }
    GBAR();

    // ============ phase C: GRU u-slice; 6 gate chains, 1 thread each ======
    if (tid < kH) {
      hpl[tid] = hG[((size_t)b * 2 + pp) * kH + tid];
      gtl[tid] = gt_g[(size_t)b * kH + tid];
    }
    __syncthreads();
    if (tid < 768) {
      int gate = tid >> 7, ul = tid & 127;
      int u = j * 128 + ul;
      const float* row; const float* vec; float acc;
      if (gate < 3) { row = dWi + (size_t)(gate * kH + u) * kH; vec = gtl; acc = dbi[gate * kH + u]; }
      else { int g2 = gate - 3; row = dWh + (size_t)(g2 * kH + u) * kH; vec = hpl; acc = dbh[g2 * kH + u]; }
      for (int k = 0; k < kH; k += 4) {
        float4 f = *(const float4*)(row + k);
        acc += vec[k] * f.x + vec[k + 1] * f.y + vec[k + 2] * f.z + vec[k + 3] * f.w;
      }
      cacc[gate][ul] = acc;
    }
    __syncthreads();
    if (tid < 128) {
      int u = j * 128 + tid;
      float air = cacc[0][tid], aiz = cacc[1][tid], ain = cacc[2][tid];
      float ahr = cacc[3][tid], ahz = cacc[4][tid], ahn = cacc[5][tid];
      float rr = 1.f / (1.f + expf(-(air + ahr)));
      float zz = 1.f / (1.f + expf(-(aiz + ahz)));
      float nn = tanhf(ain + rr * ahn);
      float hp = hpl[u];
      hG[((size_t)b * 2 + np) * kH + u] = (1.f - zz) * nn + zz * hp;
    }
    GBAR();

    // ============ phase D: logits, tiles 2j,2j+1, rows split sg pairs =====
    if (tid < kH) hnl[tid] = hG[((size_t)b * 2 + np) * kH + tid];
    __syncthreads();
    {
      float hreg[16];
#pragma unroll
      for (int m = 0; m < 16; m += 4) *(float4*)(hreg + m) = *(const float4*)(&hnl[hl * 16 + m]);
      int ct = 2 * j + p;
      int c0 = ct * 250;
      for (int ii = 0; ii < 16; ii += 2) {    // this sg's 16 of 32 i-values
        int i0 = hr * 16 + ii;
        int ca = c0 + (i0 + 0) * 8 + w * 2 + half;
        int cb = c0 + (i0 + 1) * 8 + w * 2 + half;
        int cca = ca < kVC ? ca : kVC - 1;
        int ccb = cb < kVC ? cb : kVC - 1;
        float4 va[4], vb[4];
        const float* rowa = oW + (size_t)cca * kH + hl * 16;
        const float* rowb = oW + (size_t)ccb * kH + hl * 16;
#pragma unroll
        for (int m = 0; m < 4; m++) { va[m] = *(const float4*)(rowa + m * 4); vb[m] = *(const float4*)(rowb + m * 4); }
        float acca = 0.f, accb = 0.f;
#pragma unroll
        for (int m = 0; m < 4; m++)
          acca += va[m].x * hreg[4 * m] + va[m].y * hreg[4 * m + 1] +
                  va[m].z * hreg[4 * m + 2] + va[m].w * hreg[4 * m + 3];
#pragma unroll
        for (int m = 0; m < 4; m++)
          accb += vb[m].x * hreg[4 * m] + vb[m].y * hreg[4 * m + 1] +
                  vb[m].z * hreg[4 * m + 2] + vb[m].w * hreg[4 * m + 3];
#pragma unroll
        for (int m2 = 16; m2 > 0; m2 >>= 1) acca += __shfl_xor(acca, m2, 32);
#pragma unroll
        for (int m2 = 16; m2 > 0; m2 >>= 1) accb += __shfl_xor(accb, m2, 32);
        if (ca < c0 + 250 && hl == 0) lg_g[(size_t)b * kVC + ca] = acca + ob[ca];
        if (cb < c0 + 250 && hl == 0) lg_g[(size_t)b * kVC + cb] = accb + ob[cb];
      }
    }
    GBAR();

    // ============ phase E: argmax (redundant) + lse/out0/loss (blk0) + key =
    {
      const float* lrow = lg_g + (size_t)b * kVC;
      float xv[8];
      if (tid < 256) {
        float bv = -3.4e38f; int bi = kVC;
#pragma unroll
        for (int i = 0; i < 8; i++) {
          int c = tid + i * 256;
          float x = (c < kVC) ? lrow[c] : -3.4e38f;
          xv[i] = x;
          if (x > bv) { bv = x; bi = c; }
        }
        rv[tid] = bv; ri[tid] = bi;
      }
      __syncthreads();
      for (int s = 128; s > 0; s >>= 1) {
        if (tid < s) {
          float v2 = rv[tid + s]; int i2 = ri[tid + s];
          if (v2 > rv[tid] || (v2 == rv[tid] && i2 < ri[tid])) { rv[tid] = v2; ri[tid] = i2; }
        }
        __syncthreads();
      }
      float Me = rv[0]; int nt = ri[0];
      if (blk0) {
        if (tid < 256) {
          float se = 0.f;
#pragma unroll
          for (int i = 0; i < 8; i++) { int c = tid + i * 256; if (c < kVC) se += expf(xv[i] - Me); }
          rs[tid] = se;
        }
        __syncthreads();
        for (int s = 128; s > 0; s >>= 1) {
          if (tid < s) rs[tid] += rs[tid + s];
          __syncthreads();
        }
        float lse = Me + logf(rs[0]);
        for (int c = tid; c < kVC; c += 1024)
          out0[((size_t)gb * kT + t) * kVC + c] = lrow[c] - lse;
        if (tid == 0) {
          int tg = targets[(size_t)gb * kT + t];
          float mk = maskp[(size_t)gb * kT + t];
          atomicAdd(loss, (lse - lrow[tg]) * mk * (1.f / 16384.f));  // /B /T
        }
      }
      tokr = nt;
      if (tid < 128) {    // next key rows (verbatim chain; h from hnl)
        int jr = j * 128 + tid;
        const float* row = aW + (size_t)jr * 1024 + 512;
        float acc = Atab[(size_t)nt * kH + jr];
        for (int k = 0; k < kH; k += 4) {
          float4 f = *(const float4*)(row + k);
          acc += hnl[k] * f.x + hnl[k + 1] * f.y + hnl[k + 2] * f.z + hnl[k + 3] * f.w;
        }
        key_g[(size_t)b * kH + jr] = acc;
      }
    }
    GBAR();
  }
}

// ================= round-5 per-b decoder (verified) — fallback =============
__global__ __launch_bounds__(1024, 1)
void k_dec_pb(const float* encAll, const float* cW, const float* Ctab,
              const float* dWi, const float* dWh, const float* dbi, const float* dbh,
              const float* oW, const float* ob, const float* aW, const float* Atab,
              const int* targets, const float* maskp,
              float* loss, float* out0, float* out1, int b0) {
  int b = blockIdx.x;
  int tid = threadIdx.x;
  int sg = tid >> 8, stid = tid & 255;
  int lane = stid & 63, w = stid >> 6, hl = lane & 31, half = lane >> 5;

  __shared__ float s_tile[4][128], e_tile[4][128], red[4][128];
  __shared__ float pm_s[8], pd_s[8];
  __shared__ float pctx_s[8][kH];
  __shared__ __align__(16) float sc_all[kLIN];
  __shared__ __align__(16) float key_s[kH];
  __shared__ __align__(16) float hbuf[2][kH];
  __shared__ __align__(16) float ctxl[kH];
  __shared__ __align__(16) float gt_s[kH];
  __shared__ float lg_s[kVC];
  __shared__ float rv[256]; __shared__ int ri[256]; __shared__ float rs[256];
  __shared__ float MD[2]; __shared__ float f8[8];
  __shared__ int tok_s;

  const float* encB = encAll + (size_t)b * kLIN * kH;
  int gb = b0 + b;

  for (int k = tid; k < kH; k += 1024) hbuf[0][k] = encB[(size_t)(kLIN - 1) * kH + k];
  if (tid == 0) tok_s = kSTART;
  __syncthreads();
  if (tid < kH) {
    int j = tid;
    const float* row = aW + (size_t)j * 1024 + 512;
    float acc = Atab[(size_t)kSTART * kH + j];
    for (int k = 0; k < kH; k += 4) {
      float4 f = *(const float4*)(row + k);
      acc += hbuf[0][k] * f.x + hbuf[0][k + 1] * f.y + hbuf[0][k + 2] * f.z + hbuf[0][k + 3] * f.w;
    }
    key_s[j] = acc;
  }
  __syncthreads();

  for (int t = 0; t < kT; ++t) {
    int pp = t & 1;
    const float* hprev = hbuf[pp];
    float* hnew = hbuf[1 - pp];
    float kreg[16];
#pragma unroll
    for (int m = 0; m < 16; m += 4) *(float4*)(kreg + m) = *(const float4*)(key_s + hl * 16 + m);
    for (int r = 0; r < 2; ++r) {
      int lt = sg + r * 4;
      for (int i0 = 0; i0 < 16; i0 += 2) {
        float4 v[2][4];
#pragma unroll
        for (int j = 0; j < 2; j++) {
          int ll = w * 32 + (i0 + j) * 2 + half;
          const float* row = encB + (size_t)(lt * 128 + ll) * kH + hl * 16;
#pragma unroll
          for (int m = 0; m < 4; m++) v[j][m] = *(const float4*)(row + m * 4);
        }
#pragma unroll
        for (int j = 0; j < 2; j++) {
          int ll = w * 32 + (i0 + j) * 2 + half;
          float acc = 0.f;
#pragma unroll
          for (int m = 0; m < 4; m++)
            acc += v[j][m].x * kreg[4 * m] + v[j][m].y * kreg[4 * m + 1] +
                   v[j][m].z * kreg[4 * m + 2] + v[j][m].w * kreg[4 * m + 3];
#pragma unroll
          for (int m2 = 16; m2 > 0; m2 >>= 1) acc += __shfl_xor(acc, m2, 32);
          if (hl == 0) { s_tile[sg][ll] = acc; sc_all[lt * 128 + ll] = acc; }
        }
      }
      __syncthreads();
      if (stid < 128) red[sg][stid] = s_tile[sg][stid];
      __syncthreads();
      for (int s = 64; s > 0; s >>= 1) {
        if (stid < s) red[sg][stid] = fmaxf(red[sg][stid], red[sg][stid + s]);
        __syncthreads();
      }
      float mt = red[sg][0];
      __syncthreads();
      if (stid < 128) { e_tile[sg][stid] = expf(s_tile[sg][stid] - mt); red[sg][stid] = e_tile[sg][stid]; }
      __syncthreads();
      for (int s = 64; s > 0; s >>= 1) {
        if (stid < s) red[sg][stid] += red[sg][stid + s];
        __syncthreads();
      }
      float dt = red[sg][0];
      int h0i = stid * 2;
      float cx = 0.f, cy = 0.f;
      const float* base = encB + (size_t)(lt * 128) * kH + h0i;
      for (int l0 = 0; l0 < 128; l0 += 4) {
        float2 v0 = *(const float2*)(base + (size_t)(l0 + 0) * kH);
        float2 v1 = *(const float2*)(base + (size_t)(l0 + 1) * kH);
        float2 v2 = *(const float2*)(base + (size_t)(l0 + 2) * kH);
        float2 v3 = *(const float2*)(base + (size_t)(l0 + 3) * kH);
        float e0 = e_tile[sg][l0], e1 = e_tile[sg][l0 + 1];
        float e2 = e_tile[sg][l0 + 2], e3 = e_tile[sg][l0 + 3];
        cx += e0 * v0.x; cy += e0 * v0.y;
        cx += e1 * v1.x; cy += e1 * v1.y;
        cx += e2 * v2.x; cy += e2 * v2.y;
        cx += e3 * v3.x; cy += e3 * v3.y;
      }
      pctx_s[lt][h0i] = cx; pctx_s[lt][h0i + 1] = cy;
      if (stid == 0) { pm_s[lt] = mt; pd_s[lt] = dt; }
      __syncthreads();
    }
    if (tid == 0) {
      float M = -1e30f;
      for (int i = 0; i < 8; i++) M = fmaxf(M, pm_s[i]);
      float D = 0.f;
      for (int i = 0; i < 8; i++) {
        float f = expf(pm_s[i] - M);
        f8[i] = f; D += f * pd_s[i];
      }
      MD[0] = M; MD[1] = 1.f / D;
    }
    __syncthreads();
    float M = MD[0], invD = MD[1];
    if (tid < 256) {
      int h0i = tid * 2;
      float cx = 0.f, cy = 0.f;
      for (int i = 0; i < 8; i++) { cx += f8[i] * pctx_s[i][h0i]; cy += f8[i] * pctx_s[i][h0i + 1]; }
      ctxl[h0i] = cx * invD; ctxl[h0i + 1] = cy * invD;
    }
    out1[((size_t)gb * kLIN + tid) * kT + t] = expf(sc_all[tid] - M) * invD;
    __syncthreads();
    if (tid < kH) {
      int j = tid, tk = tok_s;
      const float* row = cW + (size_t)j * 1024 + 512;
      float acc = Ctab[(size_t)tk * kH + j];
      for (int k = 0; k < kH; k += 4) {
        float4 f = *(const float4*)(row + k);
        acc += ctxl[k] * f.x + ctxl[k + 1] * f.y + ctxl[k + 2] * f.z + ctxl[k + 3] * f.w;
      }
      gt_s[j] = fmaxf(acc, 0.f);
    }
    __syncthreads();
    if (tid < kH) {
      int u = tid;
      float air = dbi[u], aiz = dbi[kH + u], ain = dbi[2 * kH + u];
      float ahr = dbh[u], ahz = dbh[kH + u], ahn = dbh[2 * kH + u];
      const float* wir = dWi + (size_t)(0 * kH + u) * kH;
      const float* wiz = dWi + (size_t)(1 * kH + u) * kH;
      const float* win = dWi + (size_t)(2 * kH + u) * kH;
      const float* whr = dWh + (size_t)(0 * kH + u) * kH;
      const float* whz = dWh + (size_t)(1 * kH + u) * kH;
      const float* whn = dWh + (size_t)(2 * kH + u) * kH;
      for (int k = 0; k < kH; k += 4) {
        float4 fir = *(const float4*)(wir + k), fiz = *(const float4*)(wiz + k), fin = *(const float4*)(win + k);
        float4 fhr = *(const float4*)(whr + k), fhz = *(const float4*)(whz + k), fhn = *(const float4*)(whn + k);
        float g0 = gt_s[k], g1 = gt_s[k + 1], g2 = gt_s[k + 2], g3 = gt_s[k + 3];
        float h0v = hprev[k], h1v = hprev[k + 1], h2v = hprev[k + 2], h3v = hprev[k + 3];
        air += g0 * fir.x + g1 * fir.y + g2 * fir.z + g3 * fir.w;
        aiz += g0 * fiz.x + g1 * fiz.y + g2 * fiz.z + g3 * fiz.w;
        ain += g0 * fin.x + g1 * fin.y + g2 * fin.z + g3 * fin.w;
        ahr += h0v * fhr.x + h1v * fhr.y + h2v * fhr.z + h3v * fhr.w;
        ahz += h0v * fhz.x + h1v * fhz.y + h2v * fhz.z + h3v * fhz.w;
        ahn += h0v * fhn.x + h1v * fhn.y + h2v * fhn.z + h3v * fhn.w;
      }
      float rr = 1.f / (1.f + expf(-(air + ahr)));
      float zz = 1.f / (1.f + expf(-(aiz + ahz)));
      float nn = tanhf(ain + rr * ahn);
      float hp = hprev[u];
      hnew[u] = (1.f - zz) * nn + zz * hp;
    }
    __syncthreads();
    {
      float hreg[16];
#pragma unroll
      for (int m = 0; m < 16; m += 4) *(float4*)(hreg + m) = *(const float4*)(&hnew[hl * 16 + m]);
      for (int r = 0; r < 2; ++r) {
        int ct = sg + r * 4;
        int c0 = ct * 250;
        for (int i0 = 0; i0 < 32; i0 += 2) {
          int ca = c0 + (i0 + 0) * 8 + w * 2 + half;
          int cb = c0 + (i0 + 1) * 8 + w * 2 + half;
          int cca = ca < kVC ? ca : kVC - 1;
          int ccb = cb < kVC ? cb : kVC - 1;
          float4 va[4], vb[4];
          const float* rowa = oW + (size_t)cca * kH + hl * 16;
          const float* rowb = oW + (size_t)ccb * kH + hl * 16;
#pragma unroll
          for (int m = 0; m < 4; m++) { va[m] = *(const float4*)(rowa + m * 4); vb[m] = *(const float4*)(rowb + m * 4); }
          float acca = 0.f, accb = 0.f;
#pragma unroll
          for (int m = 0; m < 4; m++)
            acca += va[m].x * hreg[4 * m] + va[m].y * hreg[4 * m + 1] +
                    va[m].z * hreg[4 * m + 2] + va[m].w * hreg[4 * m + 3];
#pragma unroll
          for (int m = 0; m < 4; m++)
            accb += vb[m].x * hreg[4 * m] + vb[m].y * hreg[4 * m + 1] +
                    vb[m].z * hreg[4 * m + 2] + vb[m].w * hreg[4 * m + 3];
#pragma unroll
          for (int m2 = 16; m2 > 0; m2 >>= 1) acca += __shfl_xor(acca, m2, 32);
#pragma unroll
          for (int m2 = 16; m2 > 0; m2 >>= 1) accb += __shfl_xor(accb, m2, 32);
          if (ca < c0 + 250 && hl == 0) lg_s[ca] = acca + ob[ca];
          if (cb < c0 + 250 && hl == 0) lg_s[cb] = accb + ob[cb];
        }
      }
    }
    __syncthreads();
    float xv[8];
    if (sg == 0) {
      float bv = -3.4e38f; int bi = kVC;
#pragma unroll
      for (int i = 0; i < 8; i++) {
        int c = stid + i * 256;
        float x = (c < kVC) ? lg_s[c] : -3.4e38f;
        xv[i] = x;
        if (x > bv) { bv = x; bi = c; }
      }
      rv[stid] = bv; ri[stid] = bi;
    }
    __syncthreads();
    for (int s = 128; s > 0; s >>= 1) {
      if (sg == 0 && stid < s) {
        float v2 = rv[stid + s]; int i2 = ri[stid + s];
        if (v2 > rv[stid] || (v2 == rv[stid] && i2 < ri[stid])) { rv[stid] = v2; ri[stid] = i2; }
      }
      __syncthreads();
    }
    float Me = rv[0]; int nt = ri[0];
    if (sg == 0) {
      float se = 0.f;
#pragma unroll
      for (int i = 0; i < 8; i++) { int c = stid + i * 256; if (c < kVC) se += expf(xv[i] - Me); }
      rs[stid] = se;
    }
    __syncthreads();
    for (int s = 128; s > 0; s >>= 1) {
      if (sg == 0 && stid < s) rs[stid] += rs[stid + s];
      __syncthreads();
    }
    float lse = Me + logf(rs[0]);
    for (int c = tid; c < kVC; c += 1024)
      out0[((size_t)gb * kT + t) * kVC + c] = lg_s[c] - lse;
    if (tid == 0) {
      tok_s = nt;
      int tg = targets[(size_t)gb * kT + t];
      float mk = maskp[(size_t)gb * kT + t];
      atomicAdd(loss, (lse - lg_s[tg]) * mk * (1.f / 16384.f));
    }
    if (tid < kH) {
      int j = tid;
      const float* row = aW + (size_t)j * 1024 + 512;
      float acc = Atab[(size_t)nt * kH + j];
      for (int k = 0; k < kH; k += 4) {
        float4 f = *(const float4*)(row + k);
        acc += hnew[k] * f.x + hnew[k + 1] * f.y + hnew[k + 2] * f.z + hnew[k + 3] * f.w;
      }
      key_s[j] = acc;
    }
    __syncthreads();
  }
}

__global__ void k_loss_out(float* dst, const float* loss) {
  if (threadIdx.x == 0 && blockIdx.x == 0) *dst = *loss;
}

// ---------------------------------------------------------------------------
static int g_coop = -1;      // -1 unknown, 1 works, 0 rejected -> fallback

extern "C" void kernel_launch(void* const* d_in, const int* in_sizes, int n_in,
                              void* d_out, int out_size, void* d_ws, size_t ws_size,
                              hipStream_t stream) {
  (void)in_sizes; (void)n_in;
  const int*   tok_in = (const int*)d_in[0];
  const int*   tgt    = (const int*)d_in[1];
  const float* mask   = (const float*)d_in[2];
  const float* emb_j  = (const float*)d_in[3];
  const float* emb_c  = (const float*)d_in[4];
  const float* eWif   = (const float*)d_in[5];
  const float* eWhf   = (const float*)d_in[6];
  const float* ebif   = (const float*)d_in[7];
  const float* ebhf   = (const float*)d_in[8];
  const float* eWib   = (const float*)d_in[9];
  const float* eWhb   = (const float*)d_in[10];
  const float* ebib   = (const float*)d_in[11];
  const float* ebhb   = (const float*)d_in[12];
  const float* dWi    = (const float*)d_in[13];
  const float* dWh    = (const float*)d_in[14];
  const float* dbi    = (const float*)d_in[15];
  const float* dbh    = (const float*)d_in[16];
  const float* aW     = (const float*)d_in[17];
  const float* ab     = (const float*)d_in[18];
  const float* cW     = (const float*)d_in[19];
  const float* cb     = (const float*)d_in[20];
  const float* oW     = (const float*)d_in[21];
  const float* ob     = (const float*)d_in[22];
  float* ws   = (float*)d_ws;
  float* out0 = (float*)d_out;
  float* out1 = out0 + (size_t)kB * kT * kVC;

  // ---- workspace layout (floats); scratch sized for BC=64 capacity
  const size_t GI   = 0;
  const size_t A    = GI + 107520;          // 70*2*768
  const size_t C    = A + 1024000;          // 2000*512
  const size_t SC   = C + 1024000;          // 64*1024
  const size_t PM   = SC + 65536;           // 64*8
  const size_t PD   = PM + 512;
  const size_t PCT  = PD + 512;             // 64*8*512
  const size_t GT   = PCT + 262144;         // 64*512
  const size_t HGo  = GT + 32768;           // 64*2*512
  const size_t LG   = HGo + 65536;          // 64*2000
  const size_t KEY  = LG + 128000;          // 64*512
  const size_t FLG  = KEY + 32768;          // 64*32 (uint counters, padded)
  const size_t LOSS = FLG + 2048;
  const size_t ENC  = LOSS + 1;             // + BC*1024*512

  int BC = 64;
  while (BC > 8 && (ENC + (size_t)BC * kLIN * kH) * sizeof(float) > ws_size) BC >>= 1;
  int NC = kB / BC;

  float* gi_p   = ws + GI;
  float* A_p    = ws + A;
  float* C_p    = ws + C;
  float* sc_p   = ws + SC;
  float* pm_p   = ws + PM;
  float* pd_p   = ws + PD;
  float* pct_p  = ws + PCT;
  float* gt_p   = ws + GT;
  float* hG_p   = ws + HGo;
  float* lg_p   = ws + LG;
  float* key_p  = ws + KEY;
  unsigned* flg = (unsigned*)(ws + FLG);
  float* loss_p = ws + LOSS;
  float* enc_p  = ws + ENC;

  k_zero<<<1, 256, 0, stream>>>(loss_p, 1);
  k_gi_table<<<140, 256, 0, stream>>>(emb_j, eWif, eWib, ebif, ebib, gi_p);
  k_ac_emb<<<2000, 256, 0, stream>>>(emb_c, aW, ab, cW, cb, A_p, C_p);

  for (int c = 0; c < NC; c++) {
    int b0 = c * BC;
    k_enc_pb<<<2 * BC, 256, 0, stream>>>(tok_in, eWhf, eWhb, ebhf, ebhb,
                                         gi_p, enc_p, b0);
    // zero group-barrier counters for this chunk
    k_zero<<<(2048 + 255) / 256, 256, 0, stream>>>(ws + FLG, 2048);

    bool dec_done = false;
    if (g_coop != 0) {
      void* dargs[] = {(void*)&enc_p, (void*)&cW, (void*)&C_p, (void*)&dWi,
                       (void*)&dWh, (void*)&dbi, (void*)&dbh, (void*)&oW,
                       (void*)&ob, (void*)&aW, (void*)&A_p, (void*)&tgt,
                       (void*)&mask, (void*)&sc_p, (void*)&pm_p, (void*)&pd_p,
                       (void*)&pct_p, (void*)&gt_p, (void*)&hG_p, (void*)&lg_p,
                       (void*)&key_p, (void*)&flg, (void*)&loss_p,
                       (void*)&out0, (void*)&out1, (void*)&BC, (void*)&b0};
      hipError_t e = hipLaunchCooperativeKernel(
          reinterpret_cast<void*>(k_dec_grp), dim3(kGRP * BC), dim3(1024),
          dargs, 0, stream);
      if (e == hipSuccess) { dec_done = true; if (g_coop < 0) g_coop = 1; }
      else { g_coop = 0; (void)hipGetLastError(); }
    }
    if (!dec_done) {
      k_dec_pb<<<BC, 1024, 0, stream>>>(enc_p, cW, C_p, dWi, dWh, dbi, dbh,
                                        oW, ob, aW, A_p, tgt, mask,
                                        loss_p, out0, out1, b0);
    }
  }
  k_loss_out<<<1, 64, 0, stream>>>(out0 + (size_t)out_size - 1, loss_p);
}

// Round 10
// 73906.848 us; speedup vs baseline: 3.8499x; 3.8272x over previous
//
#include <hip/hip_runtime.h>
#include <cstdint>
#include <cstddef>

// ---------------------------------------------------------------------------
// Seq2SeqNet: bidir GRU encoder (1024 steps) + attention GRU greedy decoder
// (256 steps). ALL math fp32 (greedy argmax feedback: low-precision or
// reassociated intermediates flip tokens).
//
// Structure lesson after 8 rounds of measurement:
//  - grid.sync: 6us@128 blocks, 95us@512 -> 1280 syncs fatal (r2/r4).
//  - per-b persistent decoder: only 64 CUs + 64x weight re-read (r5, 470us/step).
//  - flag barriers between blocks: agent-scope fences force L2 writeback/inv
//    at the cross-XCD coherence point every phase -> FETCH doubled, VALUBusy
//    1% (r7/r8). ANY cross-block sync in-kernel loses.
//  - Multi-launch gives each phase its ideal grid shape with no fences: the
//    proven round-0 decoder (5 kernels/step). Its waste was 1024 encoder
//    launches -> replaced by the per-(b,dir) persistent encoder k_enc_pb
//    (zero sync, LDS h-state, passed r5/r7/r8) in ONE launch.
// This file = round-0 baseline verbatim + k_enc_pb encoder.
// [Resubmission: round-9 bench was an infra failure ("container failed
//  twice") — third occurrence of this signature; both prior occurrences
//  (r3->r4, r6->r7) passed on identical resubmit. This kernel contains only
//  previously-passing components, no coop/sync/spin surface.]
// ---------------------------------------------------------------------------

constexpr int kH = 512, kH2 = 256, kVC = 2000, kB = 64, kLIN = 1024, kT = 256;
constexpr int kSTART = 1;

// -------------------------------------------------------------------- zero
__global__ __launch_bounds__(256) void k_zero(float* p, int n) {
  int i = blockIdx.x * 256 + threadIdx.x;
  if (i < n) p[i] = 0.f;
}

// ------------------------------------------- encoder input-gate token table
__global__ __launch_bounds__(256)
void k_gi_table(const float* emb_jamo, const float* Wf, const float* Wb,
                const float* bihf, const float* bihb, float* gi) {
  int v = blockIdx.x >> 1, d = blockIdx.x & 1;
  const float* W = d ? Wb : Wf;
  const float* bih = d ? bihb : bihf;
  __shared__ float x[kH];
  for (int k = threadIdx.x; k < kH; k += 256) x[k] = emb_jamo[v * kH + k];
  __syncthreads();
  for (int j = threadIdx.x; j < 3 * kH2; j += 256) {
    float acc = bih[j];
    const float* row = W + (size_t)j * kH;
    for (int k = 0; k < kH; k += 4) {
      float4 f = *(const float4*)(row + k);
      acc += x[k] * f.x + x[k + 1] * f.y + x[k + 2] * f.z + x[k + 3] * f.w;
    }
    gi[(size_t)(v * 2 + d) * 768 + j] = acc;
  }
}

// ------------------ decoder embedding tables (bias folded)
__global__ __launch_bounds__(256)
void k_ac_emb(const float* emb_char, const float* attn_W, const float* attn_b,
              const float* comb_W, const float* comb_b, float* A, float* C) {
  int v = blockIdx.x;
  __shared__ float x[kH];
  for (int k = threadIdx.x; k < kH; k += 256) x[k] = emb_char[v * kH + k];
  __syncthreads();
  for (int j = threadIdx.x; j < kH; j += 256) {
    float a = attn_b[j], c = comb_b[j];
    const float* ra = attn_W + (size_t)j * 1024;
    const float* rc = comb_W + (size_t)j * 1024;
    for (int k = 0; k < kH; k += 4) {
      float4 fa = *(const float4*)(ra + k), fc = *(const float4*)(rc + k);
      a += x[k] * fa.x + x[k + 1] * fa.y + x[k + 2] * fa.z + x[k + 3] * fa.w;
      c += x[k] * fc.x + x[k + 1] * fc.y + x[k + 2] * fc.z + x[k + 3] * fc.w;
    }
    A[(size_t)v * kH + j] = a;
    C[(size_t)v * kH + j] = c;
  }
}

// ================= persistent per-(b,dir) encoder (verified r5/r7/r8) ======
// Thread u owns hidden unit u; h vector lives in LDS; dot order identical to
// the original per-step kernel. One launch replaces 1024.
__global__ __launch_bounds__(256)
void k_enc_pb(const int* tokens, const float* Whf, const float* Whb,
              const float* bhhf, const float* bhhb, const float* gi,
              float* enc, int b0) {
  int b = blockIdx.x >> 1, d = blockIdx.x & 1;
  int u = threadIdx.x;
  const float* Whh = d ? Whb : Whf;
  const float* bhh = d ? bhhb : bhhf;
  __shared__ float hsh[kH2];
  hsh[u] = 0.f;
  __syncthreads();
  const float* wr = Whh + (size_t)(0 * kH2 + u) * kH2;
  const float* wz = Whh + (size_t)(1 * kH2 + u) * kH2;
  const float* wn = Whh + (size_t)(2 * kH2 + u) * kH2;
  float br = bhh[u], bz = bhh[kH2 + u], bn = bhh[2 * kH2 + u];
  const int* myTok = tokens + (size_t)(b0 + b) * kLIN;
  float* encCol = enc + (size_t)b * kLIN * kH + d * kH2 + u;
  for (int t = 0; t < kLIN; ++t) {
    float ar = br, az = bz, an = bn;
    for (int k = 0; k < kH2; k += 4) {
      float4 fr = *(const float4*)(wr + k);
      float4 fz = *(const float4*)(wz + k);
      float4 fn = *(const float4*)(wn + k);
      float h0v = hsh[k], h1v = hsh[k + 1], h2v = hsh[k + 2], h3v = hsh[k + 3];
      ar += h0v * fr.x + h1v * fr.y + h2v * fr.z + h3v * fr.w;
      az += h0v * fz.x + h1v * fz.y + h2v * fz.z + h3v * fz.w;
      an += h0v * fn.x + h1v * fn.y + h2v * fn.z + h3v * fn.w;
    }
    int v = myTok[t];
    const float* git = gi + (size_t)(v * 2 + d) * 768;
    float r = 1.f / (1.f + expf(-(git[u] + ar)));
    float z = 1.f / (1.f + expf(-(git[kH2 + u] + az)));
    float n = tanhf(git[2 * kH2 + u] + r * an);
    float hprev = hsh[u];
    float hnew = (1.f - z) * n + z * hprev;
    __syncthreads();               // all dot-reads of hsh done
    hsh[u] = hnew;
    encCol[(size_t)t * kH] = hnew;
    __syncthreads();               // hsh update visible before next step
  }
}

// ----------------------------------------------------- decoder prologue
__global__ __launch_bounds__(256)
void k_prologue(const float* enc, const float* Atab, const float* aW,
                float* hr, float* ht, float* key, int* tok, int BC) {
  int b = blockIdx.x, tid = threadIdx.x;
  __shared__ float h[kH];
  const float* h0 = enc + ((size_t)b * kLIN + (kLIN - 1)) * kH;
  for (int k = tid; k < kH; k += 256) {
    float v = h0[k];
    h[k] = v;
    hr[(size_t)b * kH + k] = v;          // slot 0, row layout [b][k]
    ht[(size_t)k * BC + b] = v;          // slot 0, transposed [k][b]
  }
  if (tid == 0) tok[b] = kSTART;
  __syncthreads();
  const float* A = Atab + (size_t)kSTART * kH;
  for (int j = tid; j < kH; j += 256) {
    const float* row = aW + (size_t)j * 1024 + 512;
    float acc = A[j];
    for (int k = 0; k < kH; k += 4) {
      float4 f = *(const float4*)(row + k);
      acc += h[k] * f.x + h[k + 1] * f.y + h[k + 2] * f.z + h[k + 3] * f.w;
    }
    key[(size_t)b * kH + j] = acc;
  }
}

// ------------- scores + per-tile softmax partials + per-tile ctx partials
// grid BC*8 = (b, l-tile of 128). Half-wave (32 lanes) computes one score.
__global__ __launch_bounds__(256)
void k_scores(const float* encAll, const float* keyAll, float* sc,
              float* pm, float* pd, float* pctx) {
  int b = blockIdx.x >> 3, lt = blockIdx.x & 7;
  int tid = threadIdx.x, lane = tid & 63, w = tid >> 6, hl = lane & 31, half = lane >> 5;
  __shared__ float s_tile[128], e_tile[128], red[128];
  const float* enc = encAll + (size_t)b * kLIN * kH;
  float kreg[16];
  const float* key = keyAll + (size_t)b * kH + hl * 16;
#pragma unroll
  for (int m = 0; m < 16; m += 4) *(float4*)(kreg + m) = *(const float4*)(key + m);
  for (int i = 0; i < 16; i++) {
    int ll = w * 32 + i * 2 + half;
    int l = lt * 128 + ll;
    const float* row = enc + (size_t)l * kH + hl * 16;
    float acc = 0.f;
#pragma unroll
    for (int m = 0; m < 16; m += 4) {
      float4 v = *(const float4*)(row + m);
      acc += v.x * kreg[m] + v.y * kreg[m + 1] + v.z * kreg[m + 2] + v.w * kreg[m + 3];
    }
#pragma unroll
    for (int m2 = 16; m2 > 0; m2 >>= 1) acc += __shfl_xor(acc, m2, 32);
    if (hl == 0) { s_tile[ll] = acc; sc[(size_t)b * kLIN + l] = acc; }
  }
  __syncthreads();
  if (tid < 128) red[tid] = s_tile[tid];
  __syncthreads();
  for (int s = 64; s > 0; s >>= 1) {
    if (tid < s) red[tid] = fmaxf(red[tid], red[tid + s]);
    __syncthreads();
  }
  float mt = red[0];
  __syncthreads();
  if (tid < 128) { e_tile[tid] = expf(s_tile[tid] - mt); red[tid] = e_tile[tid]; }
  __syncthreads();
  for (int s = 64; s > 0; s >>= 1) {
    if (tid < s) red[tid] += red[tid + s];
    __syncthreads();
  }
  float dt = red[0];
  int h0i = tid * 2;
  float cx = 0.f, cy = 0.f;
  const float* base = enc + (size_t)(lt * 128) * kH + h0i;
  for (int l = 0; l < 128; l++) {
    float e = e_tile[l];
    float2 v = *(const float2*)(base + (size_t)l * kH);
    cx += e * v.x; cy += e * v.y;
  }
  float* pc = pctx + ((size_t)b * 8 + lt) * kH;
  pc[h0i] = cx; pc[h0i + 1] = cy;
  if (tid == 0) { pm[b * 8 + lt] = mt; pd[b * 8 + lt] = dt; }
}

// ---- combine partials -> ctx, write attention weights, g = relu(C[tok]+ctx.Wc)
__global__ __launch_bounds__(256)
void k_ctx_g(const float* cW, const float* Ctab, const float* sc,
             const float* pm, const float* pd, const float* pctx,
             const int* tok, float* out1, float* gt, int BC, int b0, int t) {
  int b = blockIdx.x, tid = threadIdx.x;
  __shared__ float f8[8], MD[2], ctxl[kH];
  __shared__ int tokl;
  if (tid == 0) {
    float M = -1e30f;
    for (int i = 0; i < 8; i++) M = fmaxf(M, pm[b * 8 + i]);
    float D = 0.f;
    for (int i = 0; i < 8; i++) {
      float f = expf(pm[b * 8 + i] - M);
      f8[i] = f; D += f * pd[b * 8 + i];
    }
    MD[0] = M; MD[1] = 1.f / D;
    tokl = tok[b];
  }
  __syncthreads();
  float M = MD[0], invD = MD[1];
  int h0i = tid * 2;
  float cx = 0.f, cy = 0.f;
  for (int i = 0; i < 8; i++) {
    const float* pc = pctx + ((size_t)b * 8 + i) * kH + h0i;
    cx += f8[i] * pc[0]; cy += f8[i] * pc[1];
  }
  ctxl[h0i] = cx * invD; ctxl[h0i + 1] = cy * invD;
  int gb = b0 + b;
  for (int l = tid; l < kLIN; l += 256)
    out1[((size_t)gb * kLIN + l) * kT + t] = expf(sc[(size_t)b * kLIN + l] - M) * invD;
  __syncthreads();
  int tk = tokl;
  for (int j = tid; j < kH; j += 256) {
    const float* row = cW + (size_t)j * 1024 + 512;
    float acc = Ctab[(size_t)tk * kH + j];
    for (int k = 0; k < kH; k += 4) {
      float4 f = *(const float4*)(row + k);
      acc += ctxl[k] * f.x + ctxl[k + 1] * f.y + ctxl[k + 2] * f.z + ctxl[k + 3] * f.w;
    }
    gt[(size_t)j * BC + b] = fmaxf(acc, 0.f);
  }
}

// --------------------------- decoder GRU: thread per (u, b), full 512 dots
__global__ __launch_bounds__(256)
void k_gru(const float* Wih, const float* Whh, const float* bih, const float* bhh,
           const float* gt, float* ht, float* hr, int BC, int lbc, int pp) {
  int tid = threadIdx.x;
  int b = tid & (BC - 1), q = tid >> lbc;
  int u = blockIdx.x * (256 >> lbc) + q;        // [0,512)
  const float* htp = ht + (size_t)pp * kH * BC;
  float air = bih[u], aiz = bih[kH + u], ain = bih[2 * kH + u];
  float ahr = bhh[u], ahz = bhh[kH + u], ahn = bhh[2 * kH + u];
  const float* wir = Wih + (size_t)(0 * kH + u) * kH;
  const float* wiz = Wih + (size_t)(1 * kH + u) * kH;
  const float* win = Wih + (size_t)(2 * kH + u) * kH;
  const float* whr = Whh + (size_t)(0 * kH + u) * kH;
  const float* whz = Whh + (size_t)(1 * kH + u) * kH;
  const float* whn = Whh + (size_t)(2 * kH + u) * kH;
  for (int k = 0; k < kH; k += 4) {
    float4 fir = *(const float4*)(wir + k), fiz = *(const float4*)(wiz + k), fin = *(const float4*)(win + k);
    float4 fhr = *(const float4*)(whr + k), fhz = *(const float4*)(whz + k), fhn = *(const float4*)(whn + k);
    float g0 = gt[(k + 0) * BC + b], g1 = gt[(k + 1) * BC + b];
    float g2 = gt[(k + 2) * BC + b], g3 = gt[(k + 3) * BC + b];
    float h0v = htp[(k + 0) * BC + b], h1v = htp[(k + 1) * BC + b];
    float h2v = htp[(k + 2) * BC + b], h3v = htp[(k + 3) * BC + b];
    air += g0 * fir.x + g1 * fir.y + g2 * fir.z + g3 * fir.w;
    aiz += g0 * fiz.x + g1 * fiz.y + g2 * fiz.z + g3 * fiz.w;
    ain += g0 * fin.x + g1 * fin.y + g2 * fin.z + g3 * fin.w;
    ahr += h0v * fhr.x + h1v * fhr.y + h2v * fhr.z + h3v * fhr.w;
    ahz += h0v * fhz.x + h1v * fhz.y + h2v * fhz.z + h3v * fhz.w;
    ahn += h0v * fhn.x + h1v * fhn.y + h2v * fhn.z + h3v * fhn.w;
  }
  float r = 1.f / (1.f + expf(-(air + ahr)));
  float z = 1.f / (1.f + expf(-(aiz + ahz)));
  float n = tanhf(ain + r * ahn);
  float hp = htp[(size_t)u * BC + b];
  float hnew = (1.f - z) * n + z * hp;
  ht[(size_t)(1 - pp) * kH * BC + (size_t)u * BC + b] = hnew;
  hr[(size_t)(1 - pp) * BC * kH + (size_t)b * kH + u] = hnew;
}

// ----------------------------- logits: grid BC*8 = (b, c-tile of 250)
__global__ __launch_bounds__(256)
void k_logits(const float* oW, const float* ob, const float* hr, float* lg,
              int BC, int np) {
  int b = blockIdx.x >> 3, ct = blockIdx.x & 7;
  int tid = threadIdx.x, lane = tid & 63, w = tid >> 6, hl = lane & 31, half = lane >> 5;
  const float* hrow = hr + (size_t)np * BC * kH + (size_t)b * kH + hl * 16;
  float hreg[16];
#pragma unroll
  for (int m = 0; m < 16; m += 4) *(float4*)(hreg + m) = *(const float4*)(hrow + m);
  int c0 = ct * 250;
  for (int i = 0; i < 32; i++) {
    int c = c0 + i * 8 + w * 2 + half;
    if (c < c0 + 250) {
      const float* row = oW + (size_t)c * kH + hl * 16;
      float acc = 0.f;
#pragma unroll
      for (int m = 0; m < 16; m += 4) {
        float4 v = *(const float4*)(row + m);
        acc += v.x * hreg[m] + v.y * hreg[m + 1] + v.z * hreg[m + 2] + v.w * hreg[m + 3];
      }
#pragma unroll
      for (int m2 = 16; m2 > 0; m2 >>= 1) acc += __shfl_xor(acc, m2, 32);
      if (hl == 0) lg[(size_t)b * kVC + c] = acc + ob[c];
    }
  }
}

// ---- log_softmax + out0 + argmax (np semantics) + loss + next-step key
__global__ __launch_bounds__(256)
void k_finish(const float* aW, const int* targets, const float* mask,
              const float* Atab, const float* hr, const float* lg,
              float* key, int* tok, float* loss, float* out0,
              int BC, int b0, int t, int np) {
  int b = blockIdx.x, tid = threadIdx.x, gb = b0 + b;
  __shared__ float rv[256]; __shared__ int ri[256]; __shared__ float rs[256];
  __shared__ float hsh[kH];
  const float* lrow = lg + (size_t)b * kVC;
  float xv[8];
  float bv = -3.4e38f; int bi = kVC;
#pragma unroll
  for (int i = 0; i < 8; i++) {
    int c = tid + i * 256;
    float x = (c < kVC) ? lrow[c] : -3.4e38f;
    xv[i] = x;
    if (x > bv) { bv = x; bi = c; }
  }
  rv[tid] = bv; ri[tid] = bi;
  __syncthreads();
  for (int s = 128; s > 0; s >>= 1) {
    if (tid < s) {
      float v2 = rv[tid + s]; int i2 = ri[tid + s];
      if (v2 > rv[tid] || (v2 == rv[tid] && i2 < ri[tid])) { rv[tid] = v2; ri[tid] = i2; }
    }
    __syncthreads();
  }
  float M = rv[0]; int nt = ri[0];
  float se = 0.f;
#pragma unroll
  for (int i = 0; i < 8; i++) { int c = tid + i * 256; if (c < kVC) se += expf(xv[i] - M); }
  rs[tid] = se;
  __syncthreads();
  for (int s = 128; s > 0; s >>= 1) {
    if (tid < s) rs[tid] += rs[tid + s];
    __syncthreads();
  }
  float lse = M + logf(rs[0]);
  float* orow = out0 + ((size_t)gb * kT + t) * kVC;
#pragma unroll
  for (int i = 0; i < 8; i++) { int c = tid + i * 256; if (c < kVC) orow[c] = xv[i] - lse; }
  if (tid == 0) {
    tok[b] = nt;
    int tg = targets[(size_t)gb * kT + t];
    float mk = mask[(size_t)gb * kT + t];
    atomicAdd(loss, (lse - lrow[tg]) * mk * (1.f / 16384.f));  // /B /T
  }
  // next key: key[b][j] = A[nt][j] + h_new[b] . attn_W[j][512:1024]
  const float* hrow = hr + (size_t)np * BC * kH + (size_t)b * kH;
  for (int k = tid; k < kH; k += 256) hsh[k] = hrow[k];
  __syncthreads();
  const float* A = Atab + (size_t)nt * kH;
  for (int j = tid; j < kH; j += 256) {
    const float* row = aW + (size_t)j * 1024 + 512;
    float acc = A[j];
    for (int k = 0; k < kH; k += 4) {
      float4 f = *(const float4*)(row + k);
      acc += hsh[k] * f.x + hsh[k + 1] * f.y + hsh[k + 2] * f.z + hsh[k + 3] * f.w;
    }
    key[(size_t)b * kH + j] = acc;
  }
}

__global__ void k_loss_out(float* dst, const float* loss) {
  if (threadIdx.x == 0 && blockIdx.x == 0) *dst = *loss;
}

// ---------------------------------------------------------------------------
extern "C" void kernel_launch(void* const* d_in, const int* in_sizes, int n_in,
                              void* d_out, int out_size, void* d_ws, size_t ws_size,
                              hipStream_t stream) {
  (void)in_sizes; (void)n_in;
  const int*   tok_in = (const int*)d_in[0];
  const int*   tgt    = (const int*)d_in[1];
  const float* mask   = (const float*)d_in[2];
  const float* emb_j  = (const float*)d_in[3];
  const float* emb_c  = (const float*)d_in[4];
  const float* eWif   = (const float*)d_in[5];
  const float* eWhf   = (const float*)d_in[6];
  const float* ebif   = (const float*)d_in[7];
  const float* ebhf   = (const float*)d_in[8];
  const float* eWib   = (const float*)d_in[9];
  const float* eWhb   = (const float*)d_in[10];
  const float* ebib   = (const float*)d_in[11];
  const float* ebhb   = (const float*)d_in[12];
  const float* dWi    = (const float*)d_in[13];
  const float* dWh    = (const float*)d_in[14];
  const float* dbi    = (const float*)d_in[15];
  const float* dbh    = (const float*)d_in[16];
  const float* aW     = (const float*)d_in[17];
  const float* ab     = (const float*)d_in[18];
  const float* cW     = (const float*)d_in[19];
  const float* cb     = (const float*)d_in[20];
  const float* oW     = (const float*)d_in[21];
  const float* ob     = (const float*)d_in[22];
  float* ws   = (float*)d_ws;
  float* out0 = (float*)d_out;
  float* out1 = out0 + (size_t)kB * kT * kVC;

  // ---- workspace layout (floats); small state sized for BC=64 capacity
  const size_t GI = 0;
  const size_t A  = GI + 107520;            // 70*2*768
  const size_t C  = A + 1024000;            // 2000*512
  const size_t SMALL = C + 1024000;
  size_t o = SMALL;
  const size_t KEY  = o; o += 64 * 512;
  const size_t SC   = o; o += 64 * 1024;
  const size_t PM   = o; o += 512;
  const size_t PD   = o; o += 512;
  const size_t PCT  = o; o += 64 * 8 * 512;
  const size_t GT   = o; o += 512 * 64;
  const size_t HR   = o; o += 2 * 64 * 512;
  const size_t HT   = o; o += 2 * 512 * 64;
  const size_t LG   = o; o += 64 * 2000;
  const size_t TOKo = o; o += 64;
  const size_t LOSS = o; o += 1;
  const size_t ENC  = o;                    // + BC*1024*512
  const int small_n = (int)(ENC - SMALL);

  // largest batch-chunk BC that fits ws_size (constant across calls ->
  // identical launch sequence every call; graph-capture safe)
  int BC = 64;
  while (BC > 8 && (ENC + (size_t)BC * kLIN * kH) * sizeof(float) > ws_size) BC >>= 1;
  int lbc = (BC == 64) ? 6 : (BC == 32) ? 5 : (BC == 16) ? 4 : 3;
  int NC = kB / BC;
  int* tokp = (int*)(ws + TOKo);

  float* gi_p   = ws + GI;
  float* A_p    = ws + A;
  float* C_p    = ws + C;
  float* key_p  = ws + KEY;
  float* sc_p   = ws + SC;
  float* pm_p   = ws + PM;
  float* pd_p   = ws + PD;
  float* pct_p  = ws + PCT;
  float* gt_p   = ws + GT;
  float* hr_p   = ws + HR;
  float* ht_p   = ws + HT;
  float* lg_p   = ws + LG;
  float* loss_p = ws + LOSS;
  float* enc_p  = ws + ENC;

  k_zero<<<(small_n + 255) / 256, 256, 0, stream>>>(ws + SMALL, small_n);
  k_gi_table<<<140, 256, 0, stream>>>(emb_j, eWif, eWib, ebif, ebib, gi_p);
  k_ac_emb<<<2000, 256, 0, stream>>>(emb_c, aW, ab, cW, cb, A_p, C_p);

  for (int c = 0; c < NC; c++) {
    int b0 = c * BC;
    // ---- encoder: ONE persistent launch (replaces 1024 per-step launches)
    k_enc_pb<<<2 * BC, 256, 0, stream>>>(tok_in, eWhf, eWhb, ebhf, ebhb,
                                         gi_p, enc_p, b0);
    k_prologue<<<BC, 256, 0, stream>>>(enc_p, A_p, aW, hr_p, ht_p, key_p, tokp, BC);
    // ---- decoder: proven per-step kernel sequence (each phase at its
    //      ideal grid shape; no cross-block sync, no fences)
    for (int t = 0; t < kT; t++) {
      int pp = t & 1, np = 1 - pp;
      k_scores<<<BC * 8, 256, 0, stream>>>(enc_p, key_p, sc_p, pm_p, pd_p, pct_p);
      k_ctx_g<<<BC, 256, 0, stream>>>(cW, C_p, sc_p, pm_p, pd_p, pct_p,
                                      tokp, out1, gt_p, BC, b0, t);
      k_gru<<<2 * BC, 256, 0, stream>>>(dWi, dWh, dbi, dbh, gt_p,
                                        ht_p, hr_p, BC, lbc, pp);
      k_logits<<<BC * 8, 256, 0, stream>>>(oW, ob, hr_p, lg_p, BC, np);
      k_finish<<<BC, 256, 0, stream>>>(aW, tgt, mask, A_p, hr_p, lg_p,
                                       key_p, tokp, loss_p, out0,
                                       BC, b0, t, np);
    }
  }
  k_loss_out<<<1, 64, 0, stream>>>(out0 + (size_t)out_size - 1, loss_p);
}